// Round 2
// 1506.840 us; speedup vs baseline: 1.1661x; 1.1661x over previous
//
#include <hip/hip_runtime.h>
#include <stdint.h>
#include <stddef.h>

typedef _Float16 f16;
typedef _Float16 f16x8 __attribute__((ext_vector_type(8)));
typedef _Float16 f16x4_t __attribute__((ext_vector_type(4)));
typedef float floatx4 __attribute__((ext_vector_type(4)));

template <int N> struct F16Vec { typedef f16 type __attribute__((ext_vector_type(N))); };

#define BN_EPS 1e-5f

// ---------------------------------------------------------------------------
// batched LDS-tiled weight transpose-convert: W [K,N] fp32 -> Wt [N,K] fp16
// ---------------------------------------------------------------------------
struct WtJob { const float* W; f16* Wt; int K; int N; int tN; int tilebase; };
struct WtBatch { WtJob j[12]; int njobs; int ntiles; };

__global__ void k_wt_tiled(WtBatch b) {
  __shared__ float T[32][33];
  int bt = blockIdx.x;
  int i = 0;
  #pragma unroll 1
  while (i + 1 < b.njobs && bt >= b.j[i + 1].tilebase) ++i;
  WtJob J = b.j[i];
  int t = bt - J.tilebase;
  int tr = t / J.tN, tc = t - tr * J.tN;      // K-tile, N-tile
  int ty = threadIdx.x >> 5, tx = threadIdx.x & 31;
  #pragma unroll
  for (int s = 0; s < 32; s += 8) {
    int k = tr * 32 + ty + s, n = tc * 32 + tx;
    if (k < J.K && n < J.N) T[ty + s][tx] = J.W[(size_t)k * J.N + n];
  }
  __syncthreads();
  #pragma unroll
  for (int s = 0; s < 32; s += 8) {
    int n = tc * 32 + ty + s, k = tr * 32 + tx;
    if (n < J.N && k < J.K) J.Wt[(size_t)n * J.K + k] = (f16)T[tx][ty + s];
  }
}

// fp32 [n,c] -> fp16 into dst[r*ldd + coff + j]  (c % 4 == 0)
__global__ void k_cvt_cols(const float* __restrict__ src, f16* __restrict__ dst,
                           int n, int c, int ldd, int coff) {
  int t = blockIdx.x * blockDim.x + threadIdx.x;
  int cq = c >> 2;
  if (t >= n * cq) return;
  int r = t / cq, j = (t - r * cq) << 2;
  float4 v = *(const float4*)(src + (size_t)r * c + j);
  f16x4_t o; o[0] = (f16)v.x; o[1] = (f16)v.y; o[2] = (f16)v.z; o[3] = (f16)v.w;
  *(f16x4_t*)(dst + (size_t)r * ldd + coff + j) = o;
}

// ---------------------------------------------------------------------------
// CSR build (both graphs fused where possible)
// ---------------------------------------------------------------------------
__global__ void k_count2(const int* __restrict__ dL, int EL, int* __restrict__ cntL,
                         const int* __restrict__ dJ, int EJ, int* __restrict__ cntJ) {
  int t = blockIdx.x * blockDim.x + threadIdx.x;
  if (t < EL) atomicAdd(&cntL[dL[t]], 1);
  else if (t < EL + EJ) atomicAdd(&cntJ[dJ[t - EL]], 1);
}

// 1024 threads, 4 elems/thread/strip; n % 4 == 0
__global__ void k_scan4(const int* __restrict__ cnt, int n, int* __restrict__ rowstart,
                        float* __restrict__ dis) {
  __shared__ int wsum[16];
  __shared__ int carry_s;
  int tid = threadIdx.x, lane = tid & 63, wv = tid >> 6;
  if (tid == 0) { carry_s = 0; rowstart[0] = 0; }
  __syncthreads();
  for (int base = 0; base < n; base += 4096) {
    int i4 = base + tid * 4;
    int4 c = {0, 0, 0, 0};
    if (i4 < n) c = *(const int4*)(cnt + i4);
    int s0 = c.x, s1 = s0 + c.y, s2 = s1 + c.z, s3 = s2 + c.w;
    int x = s3;
    #pragma unroll
    for (int off = 1; off < 64; off <<= 1) {
      int y = __shfl_up(x, off, 64);
      if (lane >= off) x += y;
    }
    if (lane == 63) wsum[wv] = x;
    __syncthreads();
    if (wv == 0) {
      int s = (lane < 16) ? wsum[lane] : 0;
      #pragma unroll
      for (int off = 1; off < 16; off <<= 1) {
        int y = __shfl_up(s, off, 64);
        if (lane >= off) s += y;
      }
      if (lane < 16) wsum[lane] = s;
    }
    __syncthreads();
    int waveoff = (wv == 0) ? 0 : wsum[wv - 1];
    int excl = (x - s3) + waveoff + carry_s;   // exclusive prefix for this thread
    if (i4 < n) {
      rowstart[i4 + 1] = excl + s0;
      rowstart[i4 + 2] = excl + s1;
      rowstart[i4 + 3] = excl + s2;
      rowstart[i4 + 4] = excl + s3;
      dis[i4 + 0] = rsqrtf(1.0f + (float)c.x);
      dis[i4 + 1] = rsqrtf(1.0f + (float)c.y);
      dis[i4 + 2] = rsqrtf(1.0f + (float)c.z);
      dis[i4 + 3] = rsqrtf(1.0f + (float)c.w);
    }
    __syncthreads();
    if (tid == 1023) carry_s = excl + s3;
    __syncthreads();
  }
}

__global__ void k_fill2(const int* __restrict__ eiL, int EL, const int* __restrict__ rsL,
                        int* __restrict__ fillL, int* __restrict__ cixL,
                        const int* __restrict__ eiJ, int EJ, const int* __restrict__ rsJ,
                        int* __restrict__ fillJ, int* __restrict__ cixJ) {
  int t = blockIdx.x * blockDim.x + threadIdx.x;
  if (t < EL) {
    int s = eiL[t], d = eiL[EL + t];
    int pos = atomicAdd(&fillL[d], 1);
    cixL[rsL[d] + pos] = s;
  } else if (t < EL + EJ) {
    int u = t - EL;
    int s = eiJ[u], d = eiJ[EJ + u];
    int pos = atomicAdd(&fillJ[d], 1);
    cixJ[rsJ[d] + pos] = s;
  }
}

// ---------------------------------------------------------------------------
// GCN aggregation: one WAVE per node, CPL channels/lane, writes f16 into the
// concat slice (bias folded). acc fp32.
// ---------------------------------------------------------------------------
template <int CPL>
__global__ void k_gather_f16(const f16* __restrict__ xw, int C,
                             const int* __restrict__ rowstart, const int* __restrict__ colidx,
                             const float* __restrict__ dis, const float* __restrict__ bias,
                             f16* __restrict__ dst, int ldd, int coff, int n) {
  typedef typename F16Vec<CPL>::type V;
  int w = threadIdx.x >> 6, l = threadIdx.x & 63;
  int j = blockIdx.x * 4 + w;
  if (j >= n) return;
  float dj = dis[j];
  int rs = rowstart[j], re = rowstart[j + 1];
  int c0 = l * CPL;
  float acc[CPL];
  {
    V p = *(const V*)(xw + (size_t)j * C + c0);
    float s = dj * dj;
    #pragma unroll
    for (int t = 0; t < CPL; ++t) acc[t] = (float)p[t] * s;
  }
  int e = rs;
  for (; e + 2 <= re; e += 2) {
    int s0 = colidx[e], s1 = colidx[e + 1];
    float f0 = dis[s0] * dj, f1 = dis[s1] * dj;
    V p0 = *(const V*)(xw + (size_t)s0 * C + c0);
    V p1 = *(const V*)(xw + (size_t)s1 * C + c0);
    #pragma unroll
    for (int t = 0; t < CPL; ++t) acc[t] += (float)p0[t] * f0 + (float)p1[t] * f1;
  }
  if (e < re) {
    int s0 = colidx[e];
    float f0 = dis[s0] * dj;
    V p0 = *(const V*)(xw + (size_t)s0 * C + c0);
    #pragma unroll
    for (int t = 0; t < CPL; ++t) acc[t] += (float)p0[t] * f0;
  }
  V o;
  #pragma unroll
  for (int t = 0; t < CPL; ++t) o[t] = (f16)(acc[t] + bias[c0 + t]);
  *(V*)(dst + (size_t)j * ldd + coff + c0) = o;
}

// ---------------------------------------------------------------------------
// BatchNorm over f16 slice: stats -> params -> apply(+relu) in place
// ---------------------------------------------------------------------------
__global__ void k_stats(const f16* __restrict__ v, int ldd, int coff, int n, int C,
                        float* __restrict__ sum, float* __restrict__ sumsq) {
  int c = blockIdx.x * blockDim.x + threadIdx.x;
  if (c >= C) return;
  int r0 = blockIdx.y * 128, r1 = min(r0 + 128, n);
  float s = 0.f, s2 = 0.f;
  for (int r = r0; r < r1; ++r) {
    float x = (float)v[(size_t)r * ldd + coff + c];
    s += x; s2 += x * x;
  }
  atomicAdd(&sum[c], s);
  atomicAdd(&sumsq[c], s2);
}

__global__ void k_bnparam(const float* __restrict__ sum, const float* __restrict__ sumsq,
                          const float* __restrict__ gamma, const float* __restrict__ beta,
                          int n, int C, float* __restrict__ scale, float* __restrict__ shift) {
  int c = blockIdx.x * blockDim.x + threadIdx.x;
  if (c >= C) return;
  float mean = sum[c] / (float)n;
  float var = sumsq[c] / (float)n - mean * mean;
  float sc = gamma[c] * rsqrtf(var + BN_EPS);
  scale[c] = sc;
  shift[c] = beta[c] - mean * sc;
}

__global__ void k_bnapply_ip(f16* __restrict__ v, int ldd, int coff, int n, int C,
                             const float* __restrict__ scale, const float* __restrict__ shift) {
  int t = blockIdx.x * blockDim.x + threadIdx.x;
  int cq = C >> 2;
  if (t >= n * cq) return;
  int r = t / cq, c = (t - r * cq) << 2;
  f16* p = v + (size_t)r * ldd + coff + c;
  f16x4_t x = *(f16x4_t*)p;
  float4 sc = *(const float4*)(scale + c);
  float4 sh = *(const float4*)(shift + c);
  f16x4_t o;
  o[0] = (f16)fmaxf((float)x[0] * sc.x + sh.x, 0.f);
  o[1] = (f16)fmaxf((float)x[1] * sc.y + sh.y, 0.f);
  o[2] = (f16)fmaxf((float)x[2] * sc.z + sh.z, 0.f);
  o[3] = (f16)fmaxf((float)x[3] * sc.w + sh.w, 0.f);
  *(f16x4_t*)p = o;
}

// ---------------------------------------------------------------------------
// fp16 MFMA GEMM (small/odd shapes): C[M,N] = A[M,K] @ Bt[N,K]^T  (+bias,+relu)
// 128x128 tile, 4 waves, BK=32, double-buffered global_load_lds. (unchanged)
// ---------------------------------------------------------------------------
__global__ __launch_bounds__(256)
void k_gemm(const f16* __restrict__ A, int lda,
            const f16* __restrict__ Bt,
            void* __restrict__ Cv, int ldc,
            const float* __restrict__ bias, int relu, int outf,
            int M, int N, int K, int mt, int nt, int per) {
  __shared__ f16 Ash[2][128 * 32];   // 2 x 8 KB
  __shared__ f16 Bsh[2][128 * 32];
  int b = blockIdx.x;
  int g = (b & 7) * per + (b >> 3);
  if (g >= mt * nt) return;
  int tm = (g / nt) * 128, tn = (g % nt) * 128;
  int tid = threadIdx.x, l = tid & 63, w = tid >> 6;

  const f16* ag[2]; const f16* bg[2];
  uint32_t lof[2];
  #pragma unroll
  for (int j = 0; j < 2; ++j) {
    int rl = w * 32 + j * 16 + (l >> 2);
    int ck = l & 3;
    int lc = ck ^ ((rl >> 1) & 3);
    int gr = tm + rl; if (gr > M - 1) gr = M - 1;
    int gn = tn + rl; if (gn > N - 1) gn = N - 1;
    ag[j] = A + (size_t)gr * lda + lc * 8;
    bg[j] = Bt + (size_t)gn * K + lc * 8;
    lof[j] = (uint32_t)(w * 32 + j * 16) * 64;
  }

  int wm = (w >> 1) * 64, wn = (w & 1) * 64;
  int q = l >> 4, l15 = l & 15;
  uint32_t aoffb[4], boffb[4];
  #pragma unroll
  for (int i = 0; i < 4; ++i) {
    int m = wm + i * 16 + l15;
    int n2 = wn + i * 16 + l15;
    aoffb[i] = (uint32_t)(m * 32 + (q ^ ((m >> 1) & 3)) * 8) * 2;
    boffb[i] = (uint32_t)(n2 * 32 + (q ^ ((n2 >> 1) & 3)) * 8) * 2;
  }

  floatx4 acc[4][4];
  #pragma unroll
  for (int i = 0; i < 4; ++i)
    #pragma unroll
    for (int j = 0; j < 4; ++j) acc[i][j] = (floatx4){0.f, 0.f, 0.f, 0.f};

  int nk = K >> 5;
  #pragma unroll
  for (int j = 0; j < 2; ++j) {
    __builtin_amdgcn_global_load_lds(
        (const __attribute__((address_space(1))) void*)ag[j],
        (__attribute__((address_space(3))) void*)((char*)Ash + lof[j]), 16, 0, 0);
    __builtin_amdgcn_global_load_lds(
        (const __attribute__((address_space(1))) void*)bg[j],
        (__attribute__((address_space(3))) void*)((char*)Bsh + lof[j]), 16, 0, 0);
    ag[j] += 32; bg[j] += 32;
  }

  for (int i = 0; i < nk; ++i) {
    __syncthreads();
    if (i + 1 < nk) {
      uint32_t d = ((i + 1) & 1) ? 8192u : 0u;
      #pragma unroll
      for (int j = 0; j < 2; ++j) {
        __builtin_amdgcn_global_load_lds(
            (const __attribute__((address_space(1))) void*)ag[j],
            (__attribute__((address_space(3))) void*)((char*)Ash + d + lof[j]), 16, 0, 0);
        __builtin_amdgcn_global_load_lds(
            (const __attribute__((address_space(1))) void*)bg[j],
            (__attribute__((address_space(3))) void*)((char*)Bsh + d + lof[j]), 16, 0, 0);
        ag[j] += 32; bg[j] += 32;
      }
    }
    uint32_t s = (i & 1) ? 8192u : 0u;
    f16x8 af[4], bf[4];
    #pragma unroll
    for (int ii = 0; ii < 4; ++ii) {
      af[ii] = *(const f16x8*)((const char*)Ash + s + aoffb[ii]);
      bf[ii] = *(const f16x8*)((const char*)Bsh + s + boffb[ii]);
    }
    #pragma unroll
    for (int mi = 0; mi < 4; ++mi)
      #pragma unroll
      for (int ni = 0; ni < 4; ++ni)
        acc[mi][ni] = __builtin_amdgcn_mfma_f32_16x16x32_f16(af[mi], bf[ni], acc[mi][ni], 0, 0, 0);
  }

  #pragma unroll
  for (int ni = 0; ni < 4; ++ni) {
    int col = tn + wn + ni * 16 + l15;
    if (col >= N) continue;
    float bv = bias ? bias[col] : 0.f;
    #pragma unroll
    for (int mi = 0; mi < 4; ++mi) {
      int rowb = tm + wm + mi * 16 + q * 4;
      #pragma unroll
      for (int r = 0; r < 4; ++r) {
        int row = rowb + r;
        if (row < M) {
          float v = acc[mi][ni][r] + bv;
          if (relu) v = fmaxf(v, 0.f);
          if (outf) ((float*)Cv)[(size_t)row * ldc + col] = v;
          else      ((f16*)Cv)[(size_t)row * ldc + col] = (f16)v;
        }
      }
    }
  }
}

// ---------------------------------------------------------------------------
// 256x256 8-wave 8-phase GEMM (T2+T3+T4+T5 template, m201 structure):
//   C[M,N] = A[M,K] @ Bt[N,K]^T (+bias,+relu), f16 out. BK=64, 512 threads.
// LDS 128KB: buf{0,1} x { A[256 rows][8 chunks of 16B] | B[256][8] }.
// - chunk swizzle: phys_chunk = logical ^ (row&7); LINEAR DMA dest, XOR
//   pre-applied to GLOBAL source chunk and re-applied on ds_read (both-sides).
// - per K-tile: 4 phases {stage; ds_read; s_barrier; lgkmcnt(0); setprio(1);
//   16 MFMA; setprio(0); s_barrier}. Stage rotation (overwrite strictly
//   after last-reader's lgkm0+barrier, audited per-region):
//   p1: B1(t+1)->other buf; p2: A0(t+2)->cur; p3: A1(t+2)->cur; p4: B0(t+2)->cur
//   vmcnt(6) only at p4 (FIFO => all of KT t+1 landed; 6 of t+2 in flight).
// - MFMA operands SWAPPED: acc = mfma(bf, af, acc) => lane holds 4 consecutive
//   n at fixed m => f16x4 (8B) epilogue stores.
// ---------------------------------------------------------------------------
#define G_BAR()   __builtin_amdgcn_s_barrier()
#define G_LGKM0() asm volatile("s_waitcnt lgkmcnt(0)" ::: "memory")

#define MFMA_PHASE(NI, B0v, B1v)                                              \
  __builtin_amdgcn_s_setprio(1);                                              \
  _Pragma("unroll")                                                           \
  for (int mi = 0; mi < 8; ++mi) {                                            \
    acc[mi][NI] = __builtin_amdgcn_mfma_f32_16x16x32_f16(B0v, af[mi][0], acc[mi][NI], 0, 0, 0); \
    acc[mi][NI] = __builtin_amdgcn_mfma_f32_16x16x32_f16(B1v, af[mi][1], acc[mi][NI], 0, 0, 0); \
  }                                                                           \
  __builtin_amdgcn_s_setprio(0);

__global__ __launch_bounds__(512, 2)
void k_gemm256(const f16* __restrict__ A, int lda,
               const f16* __restrict__ Bt,
               f16* __restrict__ C, int ldc,
               const float* __restrict__ bias, int relu,
               int M, int N, int K, int mt, int nt) {
  __shared__ char lds[131072];
  char* ldsc = (char*)lds;
  int nwg = mt * nt;
  int b = blockIdx.x;
  // bijective XCD swizzle (m204)
  int xcd = b & 7, lid = b >> 3;
  int q8 = nwg >> 3, r8 = nwg & 7;
  int wg = (xcd < r8 ? xcd * (q8 + 1) : r8 * (q8 + 1) + (xcd - r8) * q8) + lid;
  int tm = (wg / nt) * 256, tn = (wg % nt) * 256;
  int tid = threadIdx.x, l = tid & 63, w = tid >> 6;
  int wm = w >> 2, wn = w & 3;            // 2 x 4 wave grid; wave tile 128x64
  int q = l >> 4, l15 = l & 15;
  int nk = K >> 6;

  // ---- staging: each thread owns 2 fixed (row, chunk) slots per half-tile ----
  int r0 = tid >> 3, r1 = r0 + 64;        // r1&7 == r0&7
  int ck = (tid & 7) ^ (r0 & 7);          // pre-swizzled global source chunk
  int gmA0a = tm + r0;        if (gmA0a > M - 1) gmA0a = M - 1;
  int gmA0b = tm + r1;        if (gmA0b > M - 1) gmA0b = M - 1;
  int gmA1a = tm + 128 + r0;  if (gmA1a > M - 1) gmA1a = M - 1;
  int gmA1b = tm + 128 + r1;  if (gmA1b > M - 1) gmA1b = M - 1;
  int gnB0a = tn + r0;        if (gnB0a > N - 1) gnB0a = N - 1;
  int gnB0b = tn + r1;        if (gnB0b > N - 1) gnB0b = N - 1;
  int gnB1a = tn + 128 + r0;  if (gnB1a > N - 1) gnB1a = N - 1;
  int gnB1b = tn + 128 + r1;  if (gnB1b > N - 1) gnB1b = N - 1;
  const f16* pA0a = A + (size_t)gmA0a * lda + ck * 8;
  const f16* pA0b = A + (size_t)gmA0b * lda + ck * 8;
  const f16* pA1a = A + (size_t)gmA1a * lda + ck * 8;
  const f16* pA1b = A + (size_t)gmA1b * lda + ck * 8;
  const f16* pB0a = Bt + (size_t)gnB0a * K + ck * 8;
  const f16* pB0b = Bt + (size_t)gnB0b * K + ck * 8;
  const f16* pB1a = Bt + (size_t)gnB1a * K + ck * 8;
  const f16* pB1b = Bt + (size_t)gnB1b * K + ck * 8;
  uint32_t dst0 = (uint32_t)tid * 16;

  auto ST2 = [&](const f16*& pa, const f16*& pb, uint32_t dst) {
    __builtin_amdgcn_global_load_lds(
        (const __attribute__((address_space(1))) void*)pa,
        (__attribute__((address_space(3))) void*)(ldsc + dst), 16, 0, 0);
    __builtin_amdgcn_global_load_lds(
        (const __attribute__((address_space(1))) void*)pb,
        (__attribute__((address_space(3))) void*)(ldsc + dst + 8192), 16, 0, 0);
    pa += 64; pb += 64;                   // advance one K-tile
  };
  auto SA0 = [&](uint32_t bb) { ST2(pA0a, pA0b, bb + dst0); };
  auto SA1 = [&](uint32_t bb) { ST2(pA1a, pA1b, bb + 16384u + dst0); };
  auto SB0 = [&](uint32_t bb) { ST2(pB0a, pB0b, bb + 32768u + dst0); };
  auto SB1 = [&](uint32_t bb) { ST2(pB1a, pB1b, bb + 49152u + dst0); };

  // ---- fragment read offsets (byte): row*128 + (chunk ^ (row&7))*16 ----
  uint32_t abase = (uint32_t)((wm * 128 + l15) * 128);
  uint32_t bbase = (uint32_t)(32768 + (wn * 64 + l15) * 128);
  uint32_t cof0 = (uint32_t)(((0 + q) ^ (l15 & 7)) * 16);   // ksub 0
  uint32_t cof1 = (uint32_t)(((4 + q) ^ (l15 & 7)) * 16);   // ksub 1

  floatx4 acc[8][4];
  #pragma unroll
  for (int i = 0; i < 8; ++i)
    #pragma unroll
    for (int j = 0; j < 4; ++j) acc[i][j] = (floatx4){0.f, 0.f, 0.f, 0.f};

  // ---- prologue: KT0 -> buf0 (4 half-tiles); KT1 -> buf1 (3 half-tiles) ----
  SA0(0u); SA1(0u); SB0(0u); SB1(0u);
  if (nk > 1) { SA0(65536u); SA1(65536u); SB0(65536u); }
  asm volatile("s_waitcnt vmcnt(6)" ::: "memory");   // KT0 fully landed
  G_BAR();

  f16x8 af[8][2];
  for (int t = 0; t < nk; ++t) {
    uint32_t cb = (t & 1) ? 65536u : 0u;
    uint32_t ob = 65536u - cb;
    const char* cbp = ldsc + cb;
    // ---------------- phase 1: all af + bf(ni=0); stage B1(t+1) ----------------
    if (t + 1 < nk) SB1(ob);
    #pragma unroll
    for (int mi = 0; mi < 8; ++mi) {
      af[mi][0] = *(const f16x8*)(cbp + abase + mi * 2048 + cof0);
      af[mi][1] = *(const f16x8*)(cbp + abase + mi * 2048 + cof1);
    }
    f16x8 b00 = *(const f16x8*)(cbp + bbase + cof0);
    f16x8 b01 = *(const f16x8*)(cbp + bbase + cof1);
    G_BAR(); G_LGKM0();
    MFMA_PHASE(0, b00, b01);
    G_BAR();
    // ---------------- phase 2: bf(ni=1); stage A0(t+2) ----------------
    if (t + 2 < nk) SA0(cb);
    f16x8 b10 = *(const f16x8*)(cbp + bbase + 2048 + cof0);
    f16x8 b11 = *(const f16x8*)(cbp + bbase + 2048 + cof1);
    G_BAR(); G_LGKM0();
    MFMA_PHASE(1, b10, b11);
    G_BAR();
    // ---------------- phase 3: bf(ni=2,3); stage A1(t+2) ----------------
    if (t + 2 < nk) SA1(cb);
    f16x8 b20 = *(const f16x8*)(cbp + bbase + 4096 + cof0);
    f16x8 b21 = *(const f16x8*)(cbp + bbase + 4096 + cof1);
    f16x8 b30 = *(const f16x8*)(cbp + bbase + 6144 + cof0);
    f16x8 b31 = *(const f16x8*)(cbp + bbase + 6144 + cof1);
    G_BAR(); G_LGKM0();
    MFMA_PHASE(2, b20, b21);
    G_BAR();
    // ---------------- phase 4: stage B0(t+2); counted vmcnt; no trailing bar ---
    if (t + 2 < nk) {
      SB0(cb);
      asm volatile("s_waitcnt vmcnt(6)" ::: "memory");  // KT t+1 fully landed
    } else {
      asm volatile("s_waitcnt vmcnt(0)" ::: "memory");  // tail drain
    }
    G_BAR();
    MFMA_PHASE(3, b30, b31);
  }

  // ---- epilogue: lane holds C[m][n0..n0+3] (swapped-operand layout) ----
  #pragma unroll
  for (int mi = 0; mi < 8; ++mi) {
    int m = tm + wm * 128 + mi * 16 + l15;
    if (m >= M) continue;
    f16* crow = C + (size_t)m * ldc;
    #pragma unroll
    for (int ni = 0; ni < 4; ++ni) {
      int n0 = tn + wn * 64 + ni * 16 + q * 4;
      floatx4 v = acc[mi][ni];
      if (bias) {
        float4 bv = *(const float4*)(bias + n0);
        v[0] += bv.x; v[1] += bv.y; v[2] += bv.z; v[3] += bv.w;
      }
      if (relu) {
        v[0] = fmaxf(v[0], 0.f); v[1] = fmaxf(v[1], 0.f);
        v[2] = fmaxf(v[2], 0.f); v[3] = fmaxf(v[3], 0.f);
      }
      f16x4_t o;
      o[0] = (f16)v[0]; o[1] = (f16)v[1]; o[2] = (f16)v[2]; o[3] = (f16)v[3];
      *(f16x4_t*)(crow + n0) = o;
    }
  }
}

// ---------------------------------------------------------------------------
// host orchestration
// ---------------------------------------------------------------------------
extern "C" void kernel_launch(void* const* d_in, const int* in_sizes, int n_in,
                              void* d_out, int out_size, void* d_ws, size_t ws_size,
                              hipStream_t stream) {
  (void)in_sizes; (void)n_in; (void)out_size; (void)ws_size;
  const int NL = 50000, NJ = 25000, EL = 400000, EJ = 100000;

  const float* x_l  = (const float*)d_in[0];
  const float* x_j  = (const float*)d_in[1];
  const int*   ei_l = (const int*)d_in[2];
  const int*   ei_j = (const int*)d_in[3];
  const float* lgW1 = (const float*)d_in[4];  const float* lgb1 = (const float*)d_in[5];
  const float* lgg1 = (const float*)d_in[6];  const float* lgbe1= (const float*)d_in[7];
  const float* lgW2 = (const float*)d_in[8];  const float* lgb2 = (const float*)d_in[9];
  const float* lgg2 = (const float*)d_in[10]; const float* lgbe2= (const float*)d_in[11];
  const float* lgfcW= (const float*)d_in[12]; const float* lgfcb= (const float*)d_in[13];
  const float* flW1 = (const float*)d_in[14]; const float* flb1 = (const float*)d_in[15];
  const float* flW2 = (const float*)d_in[16]; const float* flb2 = (const float*)d_in[17];
  const float* flW3 = (const float*)d_in[18]; const float* flb3 = (const float*)d_in[19];
  const float* jgW1 = (const float*)d_in[20]; const float* jgb1 = (const float*)d_in[21];
  const float* jgg1 = (const float*)d_in[22]; const float* jgbe1= (const float*)d_in[23];
  const float* jgW2 = (const float*)d_in[24]; const float* jgb2 = (const float*)d_in[25];
  const float* jgg2 = (const float*)d_in[26]; const float* jgbe2= (const float*)d_in[27];
  const float* jgfcW= (const float*)d_in[28]; const float* jgfcb= (const float*)d_in[29];
  const float* fjW1 = (const float*)d_in[30]; const float* fjb1 = (const float*)d_in[31];
  const float* fjW2 = (const float*)d_in[32]; const float* fjb2 = (const float*)d_in[33];

  char* ws = (char*)d_ws;
  size_t off = 0;
  auto alloc = [&](size_t bytes) -> char* {
    char* p = ws + off;
    off += (bytes + 255) & ~(size_t)255;
    return p;
  };

  f16* cat16 = (f16*)alloc((size_t)NL * 1792 * 2);   // [x | h1 | h2]
  f16* hA    = (f16*)alloc((size_t)NL * 1024 * 2);
  f16* hB    = (f16*)alloc((size_t)NL * 1024 * 2);
  f16*  xw16  = (f16*)hB;      // alias: GCN phase only (hB first written at fl1)
  f16* catJ  = (f16*)alloc((size_t)NJ * 448 * 2);
  f16* hJA   = (f16*)alloc((size_t)NJ * 256 * 2);
  f16* hJB   = (f16*)alloc((size_t)NJ * 64 * 2);
  f16*  xwJ   = (f16*)hB;      // junction branch runs after line branch

  f16* W1t   = (f16*)alloc((size_t)1024 * 512 * 2);
  f16* W2t   = (f16*)alloc((size_t)512 * 256 * 2);
  f16* fcWt  = (f16*)alloc((size_t)1792 * 1024 * 2);
  f16* flW1t = (f16*)alloc((size_t)1024 * 1024 * 2);
  f16* flW2t = (f16*)alloc((size_t)1024 * 1024 * 2);
  f16* flW3t = (f16*)alloc((size_t)1024 * 16 * 2);
  f16* jW1t  = (f16*)alloc((size_t)256 * 128 * 2);
  f16* jW2t  = (f16*)alloc((size_t)128 * 64 * 2);
  f16* jfcWt = (f16*)alloc((size_t)448 * 256 * 2);
  f16* fjW1t = (f16*)alloc((size_t)256 * 64 * 2);
  f16* fjW2t = (f16*)alloc((size_t)64 * 4 * 2);

  // zero-region: [cntL | fillL | cntJ | fillJ | stats(1920 f32)]
  int* zero0 = (int*)alloc(((size_t)2 * NL + 2 * NJ + 1920) * 4);
  int* cntL  = zero0;
  int* fillL = cntL + NL;
  int* cntJ  = fillL + NL;
  int* fillJ = cntJ + NJ;
  float* stats = (float*)(fillJ + NJ);
  float* sum1L = stats;        float* sq1L = stats + 512;    // C=512
  float* sum2L = stats + 1024; float* sq2L = stats + 1280;   // C=256
  float* sum1J = stats + 1536; float* sq1J = stats + 1664;   // C=128
  float* sum2J = stats + 1792; float* sq2J = stats + 1856;   // C=64

  int* rsL   = (int*)alloc((size_t)(NL + 4) * 4);
  int* cixL  = (int*)alloc((size_t)EL * 4);
  float* disL= (float*)alloc((size_t)NL * 4);
  int* rsJ   = (int*)alloc((size_t)(NJ + 4) * 4);
  int* cixJ  = (int*)alloc((size_t)EJ * 4);
  float* disJ= (float*)alloc((size_t)NJ * 4);
  float* scalc = (float*)alloc(512 * 4);
  float* shftc = (float*)alloc(512 * 4);

  auto cdiv = [](int a, int b) { return (a + b - 1) / b; };

  auto gemm = [&](const f16* A, int lda, const f16* Bt, void* Cc, int ldc,
                  const float* bias, int relu, int outf, int M, int N, int K) {
    if (!outf && (N & 255) == 0 && N >= 256 && (K & 63) == 0 && K >= 128) {
      // 256x256 8-phase path (fc, fl1, fl2, GCN1, GCN2, jfc)
      int mt = cdiv(M, 256), nt = N >> 8;
      k_gemm256<<<mt * nt, 512, 0, stream>>>(A, lda, Bt, (f16*)Cc, ldc, bias, relu,
                                             M, N, K, mt, nt);
    } else {
      int mt = cdiv(M, 128), nt = cdiv(N, 128);
      int per = cdiv(mt * nt, 8);
      k_gemm<<<8 * per, 256, 0, stream>>>(A, lda, Bt, Cc, ldc, bias, relu, outf,
                                          M, N, K, mt, nt, per);
    }
  };
  auto bn = [&](f16* v, int ldd, int coff, int n, int C,
                float* sum, float* sumsq, const float* gamma, const float* beta) {
    dim3 gs(cdiv(C, 256), cdiv(n, 128));
    k_stats<<<gs, 256, 0, stream>>>(v, ldd, coff, n, C, sum, sumsq);
    k_bnparam<<<cdiv(C, 256), 256, 0, stream>>>(sum, sumsq, gamma, beta, n, C, scalc, shftc);
    k_bnapply_ip<<<cdiv(n * (C >> 2), 256), 256, 0, stream>>>(v, ldd, coff, n, C, scalc, shftc);
  };

  // ---- one memset for all zero-init scratch ----
  hipMemsetAsync(zero0, 0, ((size_t)2 * NL + 2 * NJ + 1920) * 4, stream);

  // ---- all weight transpose-converts in ONE tiled launch ----
  {
    WtBatch B2; int base = 0, nj = 0;
    auto add = [&](const float* W, f16* Wt, int K, int N) {
      int tK = cdiv(K, 32), tN = cdiv(N, 32);
      B2.j[nj++] = WtJob{W, Wt, K, N, tN, base};
      base += tK * tN;
    };
    add(lgW1, W1t, 1024, 512);
    add(lgW2, W2t, 512, 256);
    add(lgfcW, fcWt, 1792, 1024);
    add(flW1, flW1t, 1024, 1024);
    add(flW2, flW2t, 1024, 1024);
    add(flW3, flW3t, 1024, 10);
    add(jgW1, jW1t, 256, 128);
    add(jgW2, jW2t, 128, 64);
    add(jgfcW, jfcWt, 448, 256);
    add(fjW1, fjW1t, 256, 64);
    add(fjW2, fjW2t, 64, 3);
    B2.njobs = nj; B2.ntiles = base;
    k_wt_tiled<<<base, 256, 0, stream>>>(B2);
  }

  // ---- feature conversion into concat buffers ----
  k_cvt_cols<<<cdiv(NL * 256, 256), 256, 0, stream>>>(x_l, cat16, NL, 1024, 1792, 0);
  k_cvt_cols<<<cdiv(NJ * 64, 256), 256, 0, stream>>>(x_j, catJ, NJ, 256, 448, 0);

  // ---- CSR build for both graphs ----
  k_count2<<<cdiv(EL + EJ, 256), 256, 0, stream>>>(ei_l + EL, EL, cntL, ei_j + EJ, EJ, cntJ);
  k_scan4<<<1, 1024, 0, stream>>>(cntL, NL, rsL, disL);
  k_scan4<<<1, 1024, 0, stream>>>(cntJ, NJ, rsJ, disJ);
  k_fill2<<<cdiv(EL + EJ, 256), 256, 0, stream>>>(ei_l, EL, rsL, fillL, cixL,
                                                  ei_j, EJ, rsJ, fillJ, cixJ);

  // ================= line branch =================
  // GCN layer 1: 1024 -> 512
  gemm(cat16, 1792, W1t, xw16, 512, nullptr, 0, 0, NL, 512, 1024);
  k_gather_f16<8><<<cdiv(NL, 4), 256, 0, stream>>>(xw16, 512, rsL, cixL, disL, lgb1,
                                                   cat16, 1792, 1024, NL);
  bn(cat16, 1792, 1024, NL, 512, sum1L, sq1L, lgg1, lgbe1);

  // GCN layer 2: 512 -> 256
  gemm(cat16 + 1024, 1792, W2t, xw16, 256, nullptr, 0, 0, NL, 256, 512);
  k_gather_f16<4><<<cdiv(NL, 4), 256, 0, stream>>>(xw16, 256, rsL, cixL, disL, lgb2,
                                                   cat16, 1792, 1536, NL);
  bn(cat16, 1792, 1536, NL, 256, sum2L, sq2L, lgg2, lgbe2);

  // fc over concat(1792) + fl stack + final logits (fp32 out, MFMA)
  gemm(cat16, 1792, fcWt, hA, 1024, lgfcb, 1, 0, NL, 1024, 1792);
  gemm(hA, 1024, flW1t, hB, 1024, flb1, 1, 0, NL, 1024, 1024);
  gemm(hB, 1024, flW2t, hA, 1024, flb2, 1, 0, NL, 1024, 1024);
  gemm(hA, 1024, flW3t, (float*)d_out, 10, flb3, 0, 1, NL, 10, 1024);

  // ================= junction branch =================
  gemm(catJ, 448, jW1t, xwJ, 128, nullptr, 0, 0, NJ, 128, 256);
  k_gather_f16<2><<<cdiv(NJ, 4), 256, 0, stream>>>(xwJ, 128, rsJ, cixJ, disJ, jgb1,
                                                   catJ, 448, 256, NJ);
  bn(catJ, 448, 256, NJ, 128, sum1J, sq1J, jgg1, jgbe1);

  gemm(catJ + 256, 448, jW2t, xwJ, 64, nullptr, 0, 0, NJ, 64, 128);
  k_gather_f16<1><<<cdiv(NJ, 4), 256, 0, stream>>>(xwJ, 64, rsJ, cixJ, disJ, jgb2,
                                                   catJ, 448, 384, NJ);
  bn(catJ, 448, 384, NJ, 64, sum2J, sq2J, jgg2, jgbe2);

  gemm(catJ, 448, jfcWt, hJA, 256, jgfcb, 1, 0, NJ, 256, 448);
  gemm(hJA, 256, fjW1t, hJB, 64, fjb1, 1, 0, NJ, 64, 256);
  gemm(hJB, 64, fjW2t, (float*)d_out + (size_t)NL * 10, 3, fjb2, 0, 1, NJ, 3, 64);
}

// Round 3
// 1506.145 us; speedup vs baseline: 1.1666x; 1.0005x over previous
//
#include <hip/hip_runtime.h>
#include <stdint.h>
#include <stddef.h>

typedef _Float16 f16;
typedef _Float16 f16x8 __attribute__((ext_vector_type(8)));
typedef _Float16 f16x4_t __attribute__((ext_vector_type(4)));
typedef float floatx4 __attribute__((ext_vector_type(4)));

template <int N> struct F16Vec { typedef f16 type __attribute__((ext_vector_type(N))); };

#define BN_EPS 1e-5f

// ---------------------------------------------------------------------------
// batched LDS-tiled weight transpose-convert: W [K,N] fp32 -> Wt [N,K] fp16
// ---------------------------------------------------------------------------
struct WtJob { const float* W; f16* Wt; int K; int N; int tN; int tilebase; };
struct WtBatch { WtJob j[12]; int njobs; int ntiles; };

__global__ void k_wt_tiled(WtBatch b) {
  __shared__ float T[32][33];
  int bt = blockIdx.x;
  int i = 0;
  #pragma unroll 1
  while (i + 1 < b.njobs && bt >= b.j[i + 1].tilebase) ++i;
  WtJob J = b.j[i];
  int t = bt - J.tilebase;
  int tr = t / J.tN, tc = t - tr * J.tN;      // K-tile, N-tile
  int ty = threadIdx.x >> 5, tx = threadIdx.x & 31;
  #pragma unroll
  for (int s = 0; s < 32; s += 8) {
    int k = tr * 32 + ty + s, n = tc * 32 + tx;
    if (k < J.K && n < J.N) T[ty + s][tx] = J.W[(size_t)k * J.N + n];
  }
  __syncthreads();
  #pragma unroll
  for (int s = 0; s < 32; s += 8) {
    int n = tc * 32 + ty + s, k = tr * 32 + tx;
    if (n < J.N && k < J.K) J.Wt[(size_t)n * J.K + k] = (f16)T[tx][ty + s];
  }
}

// fp32 [n,c] -> fp16 into dst[r*ldd + coff + j]  (c % 4 == 0)
__global__ void k_cvt_cols(const float* __restrict__ src, f16* __restrict__ dst,
                           int n, int c, int ldd, int coff) {
  int t = blockIdx.x * blockDim.x + threadIdx.x;
  int cq = c >> 2;
  if (t >= n * cq) return;
  int r = t / cq, j = (t - r * cq) << 2;
  float4 v = *(const float4*)(src + (size_t)r * c + j);
  f16x4_t o; o[0] = (f16)v.x; o[1] = (f16)v.y; o[2] = (f16)v.z; o[3] = (f16)v.w;
  *(f16x4_t*)(dst + (size_t)r * ldd + coff + j) = o;
}

// ---------------------------------------------------------------------------
// CSR build (both graphs fused where possible)
// ---------------------------------------------------------------------------
__global__ void k_count2(const int* __restrict__ dL, int EL, int* __restrict__ cntL,
                         const int* __restrict__ dJ, int EJ, int* __restrict__ cntJ) {
  int t = blockIdx.x * blockDim.x + threadIdx.x;
  if (t < EL) atomicAdd(&cntL[dL[t]], 1);
  else if (t < EL + EJ) atomicAdd(&cntJ[dJ[t - EL]], 1);
}

// 1024 threads, 4 elems/thread/strip; n % 4 == 0
__global__ void k_scan4(const int* __restrict__ cnt, int n, int* __restrict__ rowstart,
                        float* __restrict__ dis) {
  __shared__ int wsum[16];
  __shared__ int carry_s;
  int tid = threadIdx.x, lane = tid & 63, wv = tid >> 6;
  if (tid == 0) { carry_s = 0; rowstart[0] = 0; }
  __syncthreads();
  for (int base = 0; base < n; base += 4096) {
    int i4 = base + tid * 4;
    int4 c = {0, 0, 0, 0};
    if (i4 < n) c = *(const int4*)(cnt + i4);
    int s0 = c.x, s1 = s0 + c.y, s2 = s1 + c.z, s3 = s2 + c.w;
    int x = s3;
    #pragma unroll
    for (int off = 1; off < 64; off <<= 1) {
      int y = __shfl_up(x, off, 64);
      if (lane >= off) x += y;
    }
    if (lane == 63) wsum[wv] = x;
    __syncthreads();
    if (wv == 0) {
      int s = (lane < 16) ? wsum[lane] : 0;
      #pragma unroll
      for (int off = 1; off < 16; off <<= 1) {
        int y = __shfl_up(s, off, 64);
        if (lane >= off) s += y;
      }
      if (lane < 16) wsum[lane] = s;
    }
    __syncthreads();
    int waveoff = (wv == 0) ? 0 : wsum[wv - 1];
    int excl = (x - s3) + waveoff + carry_s;   // exclusive prefix for this thread
    if (i4 < n) {
      rowstart[i4 + 1] = excl + s0;
      rowstart[i4 + 2] = excl + s1;
      rowstart[i4 + 3] = excl + s2;
      rowstart[i4 + 4] = excl + s3;
      dis[i4 + 0] = rsqrtf(1.0f + (float)c.x);
      dis[i4 + 1] = rsqrtf(1.0f + (float)c.y);
      dis[i4 + 2] = rsqrtf(1.0f + (float)c.z);
      dis[i4 + 3] = rsqrtf(1.0f + (float)c.w);
    }
    __syncthreads();
    if (tid == 1023) carry_s = excl + s3;
    __syncthreads();
  }
}

__global__ void k_fill2(const int* __restrict__ eiL, int EL, const int* __restrict__ rsL,
                        int* __restrict__ fillL, int* __restrict__ cixL,
                        const int* __restrict__ eiJ, int EJ, const int* __restrict__ rsJ,
                        int* __restrict__ fillJ, int* __restrict__ cixJ) {
  int t = blockIdx.x * blockDim.x + threadIdx.x;
  if (t < EL) {
    int s = eiL[t], d = eiL[EL + t];
    int pos = atomicAdd(&fillL[d], 1);
    cixL[rsL[d] + pos] = s;
  } else if (t < EL + EJ) {
    int u = t - EL;
    int s = eiJ[u], d = eiJ[EJ + u];
    int pos = atomicAdd(&fillJ[d], 1);
    cixJ[rsJ[d] + pos] = s;
  }
}

// ---------------------------------------------------------------------------
// GCN aggregation: one WAVE per node, CPL channels/lane, writes f16 into the
// concat slice (bias folded). acc fp32.
// ---------------------------------------------------------------------------
template <int CPL>
__global__ void k_gather_f16(const f16* __restrict__ xw, int C,
                             const int* __restrict__ rowstart, const int* __restrict__ colidx,
                             const float* __restrict__ dis, const float* __restrict__ bias,
                             f16* __restrict__ dst, int ldd, int coff, int n) {
  typedef typename F16Vec<CPL>::type V;
  int w = threadIdx.x >> 6, l = threadIdx.x & 63;
  int j = blockIdx.x * 4 + w;
  if (j >= n) return;
  float dj = dis[j];
  int rs = rowstart[j], re = rowstart[j + 1];
  int c0 = l * CPL;
  float acc[CPL];
  {
    V p = *(const V*)(xw + (size_t)j * C + c0);
    float s = dj * dj;
    #pragma unroll
    for (int t = 0; t < CPL; ++t) acc[t] = (float)p[t] * s;
  }
  int e = rs;
  for (; e + 2 <= re; e += 2) {
    int s0 = colidx[e], s1 = colidx[e + 1];
    float f0 = dis[s0] * dj, f1 = dis[s1] * dj;
    V p0 = *(const V*)(xw + (size_t)s0 * C + c0);
    V p1 = *(const V*)(xw + (size_t)s1 * C + c0);
    #pragma unroll
    for (int t = 0; t < CPL; ++t) acc[t] += (float)p0[t] * f0 + (float)p1[t] * f1;
  }
  if (e < re) {
    int s0 = colidx[e];
    float f0 = dis[s0] * dj;
    V p0 = *(const V*)(xw + (size_t)s0 * C + c0);
    #pragma unroll
    for (int t = 0; t < CPL; ++t) acc[t] += (float)p0[t] * f0;
  }
  V o;
  #pragma unroll
  for (int t = 0; t < CPL; ++t) o[t] = (f16)(acc[t] + bias[c0 + t]);
  *(V*)(dst + (size_t)j * ldd + coff + c0) = o;
}

// ---------------------------------------------------------------------------
// BatchNorm over f16 slice: stats -> params -> apply(+relu) in place
// ---------------------------------------------------------------------------
__global__ void k_stats(const f16* __restrict__ v, int ldd, int coff, int n, int C,
                        float* __restrict__ sum, float* __restrict__ sumsq) {
  int c = blockIdx.x * blockDim.x + threadIdx.x;
  if (c >= C) return;
  int r0 = blockIdx.y * 128, r1 = min(r0 + 128, n);
  float s = 0.f, s2 = 0.f;
  for (int r = r0; r < r1; ++r) {
    float x = (float)v[(size_t)r * ldd + coff + c];
    s += x; s2 += x * x;
  }
  atomicAdd(&sum[c], s);
  atomicAdd(&sumsq[c], s2);
}

__global__ void k_bnparam(const float* __restrict__ sum, const float* __restrict__ sumsq,
                          const float* __restrict__ gamma, const float* __restrict__ beta,
                          int n, int C, float* __restrict__ scale, float* __restrict__ shift) {
  int c = blockIdx.x * blockDim.x + threadIdx.x;
  if (c >= C) return;
  float mean = sum[c] / (float)n;
  float var = sumsq[c] / (float)n - mean * mean;
  float sc = gamma[c] * rsqrtf(var + BN_EPS);
  scale[c] = sc;
  shift[c] = beta[c] - mean * sc;
}

__global__ void k_bnapply_ip(f16* __restrict__ v, int ldd, int coff, int n, int C,
                             const float* __restrict__ scale, const float* __restrict__ shift) {
  int t = blockIdx.x * blockDim.x + threadIdx.x;
  int cq = C >> 2;
  if (t >= n * cq) return;
  int r = t / cq, c = (t - r * cq) << 2;
  f16* p = v + (size_t)r * ldd + coff + c;
  f16x4_t x = *(f16x4_t*)p;
  float4 sc = *(const float4*)(scale + c);
  float4 sh = *(const float4*)(shift + c);
  f16x4_t o;
  o[0] = (f16)fmaxf((float)x[0] * sc.x + sh.x, 0.f);
  o[1] = (f16)fmaxf((float)x[1] * sc.y + sh.y, 0.f);
  o[2] = (f16)fmaxf((float)x[2] * sc.z + sh.z, 0.f);
  o[3] = (f16)fmaxf((float)x[3] * sc.w + sh.w, 0.f);
  *(f16x4_t*)p = o;
}

// ---------------------------------------------------------------------------
// fp16 MFMA GEMM (small/odd shapes): C[M,N] = A[M,K] @ Bt[N,K]^T  (+bias,+relu)
// 128x128 tile, 4 waves, BK=32, double-buffered global_load_lds. (unchanged)
// ---------------------------------------------------------------------------
__global__ __launch_bounds__(256)
void k_gemm(const f16* __restrict__ A, int lda,
            const f16* __restrict__ Bt,
            void* __restrict__ Cv, int ldc,
            const float* __restrict__ bias, int relu, int outf,
            int M, int N, int K, int mt, int nt, int per) {
  __shared__ f16 Ash[2][128 * 32];   // 2 x 8 KB
  __shared__ f16 Bsh[2][128 * 32];
  int b = blockIdx.x;
  int g = (b & 7) * per + (b >> 3);
  if (g >= mt * nt) return;
  int tm = (g / nt) * 128, tn = (g % nt) * 128;
  int tid = threadIdx.x, l = tid & 63, w = tid >> 6;

  const f16* ag[2]; const f16* bg[2];
  uint32_t lof[2];
  #pragma unroll
  for (int j = 0; j < 2; ++j) {
    int rl = w * 32 + j * 16 + (l >> 2);
    int ck = l & 3;
    int lc = ck ^ ((rl >> 1) & 3);
    int gr = tm + rl; if (gr > M - 1) gr = M - 1;
    int gn = tn + rl; if (gn > N - 1) gn = N - 1;
    ag[j] = A + (size_t)gr * lda + lc * 8;
    bg[j] = Bt + (size_t)gn * K + lc * 8;
    lof[j] = (uint32_t)(w * 32 + j * 16) * 64;
  }

  int wm = (w >> 1) * 64, wn = (w & 1) * 64;
  int q = l >> 4, l15 = l & 15;
  uint32_t aoffb[4], boffb[4];
  #pragma unroll
  for (int i = 0; i < 4; ++i) {
    int m = wm + i * 16 + l15;
    int n2 = wn + i * 16 + l15;
    aoffb[i] = (uint32_t)(m * 32 + (q ^ ((m >> 1) & 3)) * 8) * 2;
    boffb[i] = (uint32_t)(n2 * 32 + (q ^ ((n2 >> 1) & 3)) * 8) * 2;
  }

  floatx4 acc[4][4];
  #pragma unroll
  for (int i = 0; i < 4; ++i)
    #pragma unroll
    for (int j = 0; j < 4; ++j) acc[i][j] = (floatx4){0.f, 0.f, 0.f, 0.f};

  int nk = K >> 5;
  #pragma unroll
  for (int j = 0; j < 2; ++j) {
    __builtin_amdgcn_global_load_lds(
        (const __attribute__((address_space(1))) void*)ag[j],
        (__attribute__((address_space(3))) void*)((char*)Ash + lof[j]), 16, 0, 0);
    __builtin_amdgcn_global_load_lds(
        (const __attribute__((address_space(1))) void*)bg[j],
        (__attribute__((address_space(3))) void*)((char*)Bsh + lof[j]), 16, 0, 0);
    ag[j] += 32; bg[j] += 32;
  }

  for (int i = 0; i < nk; ++i) {
    __syncthreads();
    if (i + 1 < nk) {
      uint32_t d = ((i + 1) & 1) ? 8192u : 0u;
      #pragma unroll
      for (int j = 0; j < 2; ++j) {
        __builtin_amdgcn_global_load_lds(
            (const __attribute__((address_space(1))) void*)ag[j],
            (__attribute__((address_space(3))) void*)((char*)Ash + d + lof[j]), 16, 0, 0);
        __builtin_amdgcn_global_load_lds(
            (const __attribute__((address_space(1))) void*)bg[j],
            (__attribute__((address_space(3))) void*)((char*)Bsh + d + lof[j]), 16, 0, 0);
        ag[j] += 32; bg[j] += 32;
      }
    }
    uint32_t s = (i & 1) ? 8192u : 0u;
    f16x8 af[4], bf[4];
    #pragma unroll
    for (int ii = 0; ii < 4; ++ii) {
      af[ii] = *(const f16x8*)((const char*)Ash + s + aoffb[ii]);
      bf[ii] = *(const f16x8*)((const char*)Bsh + s + boffb[ii]);
    }
    #pragma unroll
    for (int mi = 0; mi < 4; ++mi)
      #pragma unroll
      for (int ni = 0; ni < 4; ++ni)
        acc[mi][ni] = __builtin_amdgcn_mfma_f32_16x16x32_f16(af[mi], bf[ni], acc[mi][ni], 0, 0, 0);
  }

  #pragma unroll
  for (int ni = 0; ni < 4; ++ni) {
    int col = tn + wn + ni * 16 + l15;
    if (col >= N) continue;
    float bv = bias ? bias[col] : 0.f;
    #pragma unroll
    for (int mi = 0; mi < 4; ++mi) {
      int rowb = tm + wm + mi * 16 + q * 4;
      #pragma unroll
      for (int r = 0; r < 4; ++r) {
        int row = rowb + r;
        if (row < M) {
          float v = acc[mi][ni][r] + bv;
          if (relu) v = fmaxf(v, 0.f);
          if (outf) ((float*)Cv)[(size_t)row * ldc + col] = v;
          else      ((f16*)Cv)[(size_t)row * ldc + col] = (f16)v;
        }
      }
    }
  }
}

// ---------------------------------------------------------------------------
// 256x256 8-wave GEMM, mi-pair 4-phase schedule (v3):
//   C[M,N] = A[M,K] @ Bt[N,K]^T (+bias,+relu), f16 out. BK=64, 512 threads.
// LDS 128KB: buf{0,1} x { A[256][8x16B] | B[256][8x16B] }, chunk-XOR swizzle
// (both-sides: pre-swizzled global source + XOR on ds_read; DMA dest linear).
// Phase p (p=0..3) = MFMA of mi-pair {2p,2p+1} x all ni x 2 ksub (16 MFMA).
// Reads are same-phase-use: p0 reads bf[4][2]+af pair0 (12), p1-p3 read one
// af pair (4 each) -> balanced LDS port load, 1 barrier per phase.
// Stage rotation (distance-2 for B, distance-1 for A; audited):
//   p0: SA0(t+1->ob)  [A0(t-1) last read p3(t-1); all waves past p0 BAR]
//   p1: SA1(t+1->ob)
//   p2: SB0(t+2->cb)  [bf(t) reads done p0(t), >=2 barriers earlier]
//   p3: SB1(t+2->cb)
// vmcnt(4)+BAR at p0 head retires A(t)+B(t) (leaves B(t+1) 4 loads in
// flight); vmcnt(0) on last iter. Prologue: KT0 (8 loads) + B(1) (4 loads).
// MFMA operands SWAPPED: acc = mfma(bf, af, acc) => lane holds 4 consecutive
// n at fixed m => f16x4 epilogue stores.
// ---------------------------------------------------------------------------
#define G_BAR()   asm volatile("s_barrier" ::: "memory")
#define G_LGKM0() asm volatile("s_waitcnt lgkmcnt(0)" ::: "memory")

#define READ_BF_ALL()                                                         \
  _Pragma("unroll")                                                           \
  for (int ni = 0; ni < 4; ++ni) {                                            \
    bf[ni][0] = *(const f16x8*)(cbp + bbase + ni * 2048 + cof0);              \
    bf[ni][1] = *(const f16x8*)(cbp + bbase + ni * 2048 + cof1);              \
  }

#define READ_AFP(P)                                                           \
  afp[0][0] = *(const f16x8*)(cbp + abase + (2 * (P)) * 2048 + cof0);         \
  afp[0][1] = *(const f16x8*)(cbp + abase + (2 * (P)) * 2048 + cof1);         \
  afp[1][0] = *(const f16x8*)(cbp + abase + (2 * (P) + 1) * 2048 + cof0);     \
  afp[1][1] = *(const f16x8*)(cbp + abase + (2 * (P) + 1) * 2048 + cof1);

#define MFMA_PAIR(P)                                                          \
  __builtin_amdgcn_s_setprio(1);                                              \
  _Pragma("unroll")                                                           \
  for (int ni = 0; ni < 4; ++ni) {                                            \
    acc[2*(P)][ni]   = __builtin_amdgcn_mfma_f32_16x16x32_f16(bf[ni][0], afp[0][0], acc[2*(P)][ni], 0, 0, 0);   \
    acc[2*(P)][ni]   = __builtin_amdgcn_mfma_f32_16x16x32_f16(bf[ni][1], afp[0][1], acc[2*(P)][ni], 0, 0, 0);   \
    acc[2*(P)+1][ni] = __builtin_amdgcn_mfma_f32_16x16x32_f16(bf[ni][0], afp[1][0], acc[2*(P)+1][ni], 0, 0, 0); \
    acc[2*(P)+1][ni] = __builtin_amdgcn_mfma_f32_16x16x32_f16(bf[ni][1], afp[1][1], acc[2*(P)+1][ni], 0, 0, 0); \
  }                                                                           \
  __builtin_amdgcn_s_setprio(0);

__global__ __launch_bounds__(512, 2)
void k_gemm256(const f16* __restrict__ A, int lda,
               const f16* __restrict__ Bt,
               f16* __restrict__ C, int ldc,
               const float* __restrict__ bias, int relu,
               int M, int N, int K, int mt, int nt) {
  __shared__ char lds[131072];
  char* ldsc = (char*)lds;
  int nwg = mt * nt;
  int b = blockIdx.x;
  // bijective XCD swizzle (m204)
  int xcd = b & 7, lid = b >> 3;
  int q8 = nwg >> 3, r8 = nwg & 7;
  int wg = (xcd < r8 ? xcd * (q8 + 1) : r8 * (q8 + 1) + (xcd - r8) * q8) + lid;
  int tm = (wg / nt) * 256, tn = (wg % nt) * 256;
  int tid = threadIdx.x, l = tid & 63, w = tid >> 6;
  int wm = w >> 2, wn = w & 3;            // 2 x 4 wave grid; wave tile 128x64
  int q = l >> 4, l15 = l & 15;
  int nk = K >> 6;

  // ---- staging: each thread owns 2 fixed (row, chunk) slots per half-tile ----
  int r0 = tid >> 3, r1 = r0 + 64;        // r1&7 == r0&7
  int ck = (tid & 7) ^ (r0 & 7);          // pre-swizzled global source chunk
  int gmA0a = tm + r0;        if (gmA0a > M - 1) gmA0a = M - 1;
  int gmA0b = tm + r1;        if (gmA0b > M - 1) gmA0b = M - 1;
  int gmA1a = tm + 128 + r0;  if (gmA1a > M - 1) gmA1a = M - 1;
  int gmA1b = tm + 128 + r1;  if (gmA1b > M - 1) gmA1b = M - 1;
  int gnB0a = tn + r0;        if (gnB0a > N - 1) gnB0a = N - 1;
  int gnB0b = tn + r1;        if (gnB0b > N - 1) gnB0b = N - 1;
  int gnB1a = tn + 128 + r0;  if (gnB1a > N - 1) gnB1a = N - 1;
  int gnB1b = tn + 128 + r1;  if (gnB1b > N - 1) gnB1b = N - 1;
  const f16* pA0a = A + (size_t)gmA0a * lda + ck * 8;
  const f16* pA0b = A + (size_t)gmA0b * lda + ck * 8;
  const f16* pA1a = A + (size_t)gmA1a * lda + ck * 8;
  const f16* pA1b = A + (size_t)gmA1b * lda + ck * 8;
  const f16* pB0a = Bt + (size_t)gnB0a * K + ck * 8;
  const f16* pB0b = Bt + (size_t)gnB0b * K + ck * 8;
  const f16* pB1a = Bt + (size_t)gnB1a * K + ck * 8;
  const f16* pB1b = Bt + (size_t)gnB1b * K + ck * 8;
  uint32_t dst0 = (uint32_t)tid * 16;

  auto ST2 = [&](const f16*& pa, const f16*& pb, uint32_t dst) {
    __builtin_amdgcn_global_load_lds(
        (const __attribute__((address_space(1))) void*)pa,
        (__attribute__((address_space(3))) void*)(ldsc + dst), 16, 0, 0);
    __builtin_amdgcn_global_load_lds(
        (const __attribute__((address_space(1))) void*)pb,
        (__attribute__((address_space(3))) void*)(ldsc + dst + 8192), 16, 0, 0);
    pa += 64; pb += 64;                   // advance one K-tile
  };
  auto SA0 = [&](uint32_t bb) { ST2(pA0a, pA0b, bb + dst0); };
  auto SA1 = [&](uint32_t bb) { ST2(pA1a, pA1b, bb + 16384u + dst0); };
  auto SB0 = [&](uint32_t bb) { ST2(pB0a, pB0b, bb + 32768u + dst0); };
  auto SB1 = [&](uint32_t bb) { ST2(pB1a, pB1b, bb + 49152u + dst0); };

  // ---- fragment read offsets (byte): row*128 + (chunk ^ (row&7))*16 ----
  uint32_t abase = (uint32_t)((wm * 128 + l15) * 128);
  uint32_t bbase = (uint32_t)(32768 + (wn * 64 + l15) * 128);
  uint32_t cof0 = (uint32_t)(((0 + q) ^ (l15 & 7)) * 16);   // ksub 0
  uint32_t cof1 = (uint32_t)(((4 + q) ^ (l15 & 7)) * 16);   // ksub 1

  floatx4 acc[8][4];
  #pragma unroll
  for (int i = 0; i < 8; ++i)
    #pragma unroll
    for (int j = 0; j < 4; ++j) acc[i][j] = (floatx4){0.f, 0.f, 0.f, 0.f};

  // ---- prologue: KT0 (8 loads, oldest) then B(1) (4 loads) ----
  SA0(0u); SA1(0u); SB0(0u); SB1(0u);
  if (nk > 1) { SB0(65536u); SB1(65536u); }

  f16x8 bf[4][2], afp[2][2];
  for (int t = 0; t < nk; ++t) {
    uint32_t cb = (t & 1) ? 65536u : 0u;
    uint32_t ob = 65536u - cb;
    const char* cbp = ldsc + cb;
    // ---- p0: vmcnt gate + all bf + af pair0; stage A0(t+1) ----
    if (t + 1 < nk) { asm volatile("s_waitcnt vmcnt(4)" ::: "memory"); }
    else            { asm volatile("s_waitcnt vmcnt(0)" ::: "memory"); }
    G_BAR();
    if (t + 1 < nk) SA0(ob);
    READ_BF_ALL();
    READ_AFP(0);
    G_LGKM0();
    MFMA_PAIR(0);
    G_BAR();
    // ---- p1: af pair1; stage A1(t+1) ----
    if (t + 1 < nk) SA1(ob);
    READ_AFP(1);
    G_LGKM0();
    MFMA_PAIR(1);
    G_BAR();
    // ---- p2: af pair2; stage B0(t+2) ----
    if (t + 2 < nk) SB0(cb);
    READ_AFP(2);
    G_LGKM0();
    MFMA_PAIR(2);
    G_BAR();
    // ---- p3: af pair3; stage B1(t+2); no trailing bar (p0's BAR covers) ----
    if (t + 2 < nk) SB1(cb);
    READ_AFP(3);
    G_LGKM0();
    MFMA_PAIR(3);
  }

  // ---- epilogue: lane holds C[m][n0..n0+3] (swapped-operand layout) ----
  #pragma unroll
  for (int mi = 0; mi < 8; ++mi) {
    int m = tm + wm * 128 + mi * 16 + l15;
    if (m >= M) continue;
    f16* crow = C + (size_t)m * ldc;
    #pragma unroll
    for (int ni = 0; ni < 4; ++ni) {
      int n0 = tn + wn * 64 + ni * 16 + q * 4;
      floatx4 v = acc[mi][ni];
      if (bias) {
        float4 bv = *(const float4*)(bias + n0);
        v[0] += bv.x; v[1] += bv.y; v[2] += bv.z; v[3] += bv.w;
      }
      if (relu) {
        v[0] = fmaxf(v[0], 0.f); v[1] = fmaxf(v[1], 0.f);
        v[2] = fmaxf(v[2], 0.f); v[3] = fmaxf(v[3], 0.f);
      }
      f16x4_t o;
      o[0] = (f16)v[0]; o[1] = (f16)v[1]; o[2] = (f16)v[2]; o[3] = (f16)v[3];
      *(f16x4_t*)(crow + n0) = o;
    }
  }
}

// ---------------------------------------------------------------------------
// host orchestration
// ---------------------------------------------------------------------------
extern "C" void kernel_launch(void* const* d_in, const int* in_sizes, int n_in,
                              void* d_out, int out_size, void* d_ws, size_t ws_size,
                              hipStream_t stream) {
  (void)in_sizes; (void)n_in; (void)out_size; (void)ws_size;
  const int NL = 50000, NJ = 25000, EL = 400000, EJ = 100000;

  const float* x_l  = (const float*)d_in[0];
  const float* x_j  = (const float*)d_in[1];
  const int*   ei_l = (const int*)d_in[2];
  const int*   ei_j = (const int*)d_in[3];
  const float* lgW1 = (const float*)d_in[4];  const float* lgb1 = (const float*)d_in[5];
  const float* lgg1 = (const float*)d_in[6];  const float* lgbe1= (const float*)d_in[7];
  const float* lgW2 = (const float*)d_in[8];  const float* lgb2 = (const float*)d_in[9];
  const float* lgg2 = (const float*)d_in[10]; const float* lgbe2= (const float*)d_in[11];
  const float* lgfcW= (const float*)d_in[12]; const float* lgfcb= (const float*)d_in[13];
  const float* flW1 = (const float*)d_in[14]; const float* flb1 = (const float*)d_in[15];
  const float* flW2 = (const float*)d_in[16]; const float* flb2 = (const float*)d_in[17];
  const float* flW3 = (const float*)d_in[18]; const float* flb3 = (const float*)d_in[19];
  const float* jgW1 = (const float*)d_in[20]; const float* jgb1 = (const float*)d_in[21];
  const float* jgg1 = (const float*)d_in[22]; const float* jgbe1= (const float*)d_in[23];
  const float* jgW2 = (const float*)d_in[24]; const float* jgb2 = (const float*)d_in[25];
  const float* jgg2 = (const float*)d_in[26]; const float* jgbe2= (const float*)d_in[27];
  const float* jgfcW= (const float*)d_in[28]; const float* jgfcb= (const float*)d_in[29];
  const float* fjW1 = (const float*)d_in[30]; const float* fjb1 = (const float*)d_in[31];
  const float* fjW2 = (const float*)d_in[32]; const float* fjb2 = (const float*)d_in[33];

  char* ws = (char*)d_ws;
  size_t off = 0;
  auto alloc = [&](size_t bytes) -> char* {
    char* p = ws + off;
    off += (bytes + 255) & ~(size_t)255;
    return p;
  };

  f16* cat16 = (f16*)alloc((size_t)NL * 1792 * 2);   // [x | h1 | h2]
  f16* hA    = (f16*)alloc((size_t)NL * 1024 * 2);
  f16* hB    = (f16*)alloc((size_t)NL * 1024 * 2);
  f16*  xw16  = (f16*)hB;      // alias: GCN phase only (hB first written at fl1)
  f16* catJ  = (f16*)alloc((size_t)NJ * 448 * 2);
  f16* hJA   = (f16*)alloc((size_t)NJ * 256 * 2);
  f16* hJB   = (f16*)alloc((size_t)NJ * 64 * 2);
  f16*  xwJ   = (f16*)hB;      // junction branch runs after line branch

  f16* W1t   = (f16*)alloc((size_t)1024 * 512 * 2);
  f16* W2t   = (f16*)alloc((size_t)512 * 256 * 2);
  f16* fcWt  = (f16*)alloc((size_t)1792 * 1024 * 2);
  f16* flW1t = (f16*)alloc((size_t)1024 * 1024 * 2);
  f16* flW2t = (f16*)alloc((size_t)1024 * 1024 * 2);
  f16* flW3t = (f16*)alloc((size_t)1024 * 16 * 2);
  f16* jW1t  = (f16*)alloc((size_t)256 * 128 * 2);
  f16* jW2t  = (f16*)alloc((size_t)128 * 64 * 2);
  f16* jfcWt = (f16*)alloc((size_t)448 * 256 * 2);
  f16* fjW1t = (f16*)alloc((size_t)256 * 64 * 2);
  f16* fjW2t = (f16*)alloc((size_t)64 * 4 * 2);

  // zero-region: [cntL | fillL | cntJ | fillJ | stats(1920 f32)]
  int* zero0 = (int*)alloc(((size_t)2 * NL + 2 * NJ + 1920) * 4);
  int* cntL  = zero0;
  int* fillL = cntL + NL;
  int* cntJ  = fillL + NL;
  int* fillJ = cntJ + NJ;
  float* stats = (float*)(fillJ + NJ);
  float* sum1L = stats;        float* sq1L = stats + 512;    // C=512
  float* sum2L = stats + 1024; float* sq2L = stats + 1280;   // C=256
  float* sum1J = stats + 1536; float* sq1J = stats + 1664;   // C=128
  float* sum2J = stats + 1792; float* sq2J = stats + 1856;   // C=64

  int* rsL   = (int*)alloc((size_t)(NL + 4) * 4);
  int* cixL  = (int*)alloc((size_t)EL * 4);
  float* disL= (float*)alloc((size_t)NL * 4);
  int* rsJ   = (int*)alloc((size_t)(NJ + 4) * 4);
  int* cixJ  = (int*)alloc((size_t)EJ * 4);
  float* disJ= (float*)alloc((size_t)NJ * 4);
  float* scalc = (float*)alloc(512 * 4);
  float* shftc = (float*)alloc(512 * 4);

  auto cdiv = [](int a, int b) { return (a + b - 1) / b; };

  auto gemm = [&](const f16* A, int lda, const f16* Bt, void* Cc, int ldc,
                  const float* bias, int relu, int outf, int M, int N, int K) {
    if (!outf && (N & 255) == 0 && N >= 256 && (K & 63) == 0 && K >= 128) {
      // 256x256 4-phase mi-pair path (fc, fl1, fl2, GCN1, GCN2, jfc)
      int mt = cdiv(M, 256), nt = N >> 8;
      k_gemm256<<<mt * nt, 512, 0, stream>>>(A, lda, Bt, (f16*)Cc, ldc, bias, relu,
                                             M, N, K, mt, nt);
    } else {
      int mt = cdiv(M, 128), nt = cdiv(N, 128);
      int per = cdiv(mt * nt, 8);
      k_gemm<<<8 * per, 256, 0, stream>>>(A, lda, Bt, Cc, ldc, bias, relu, outf,
                                          M, N, K, mt, nt, per);
    }
  };
  auto bn = [&](f16* v, int ldd, int coff, int n, int C,
                float* sum, float* sumsq, const float* gamma, const float* beta) {
    dim3 gs(cdiv(C, 256), cdiv(n, 128));
    k_stats<<<gs, 256, 0, stream>>>(v, ldd, coff, n, C, sum, sumsq);
    k_bnparam<<<cdiv(C, 256), 256, 0, stream>>>(sum, sumsq, gamma, beta, n, C, scalc, shftc);
    k_bnapply_ip<<<cdiv(n * (C >> 2), 256), 256, 0, stream>>>(v, ldd, coff, n, C, scalc, shftc);
  };

  // ---- one memset for all zero-init scratch ----
  hipMemsetAsync(zero0, 0, ((size_t)2 * NL + 2 * NJ + 1920) * 4, stream);

  // ---- all weight transpose-converts in ONE tiled launch ----
  {
    WtBatch B2; int base = 0, nj = 0;
    auto add = [&](const float* W, f16* Wt, int K, int N) {
      int tK = cdiv(K, 32), tN = cdiv(N, 32);
      B2.j[nj++] = WtJob{W, Wt, K, N, tN, base};
      base += tK * tN;
    };
    add(lgW1, W1t, 1024, 512);
    add(lgW2, W2t, 512, 256);
    add(lgfcW, fcWt, 1792, 1024);
    add(flW1, flW1t, 1024, 1024);
    add(flW2, flW2t, 1024, 1024);
    add(flW3, flW3t, 1024, 10);
    add(jgW1, jW1t, 256, 128);
    add(jgW2, jW2t, 128, 64);
    add(jgfcW, jfcWt, 448, 256);
    add(fjW1, fjW1t, 256, 64);
    add(fjW2, fjW2t, 64, 3);
    B2.njobs = nj; B2.ntiles = base;
    k_wt_tiled<<<base, 256, 0, stream>>>(B2);
  }

  // ---- feature conversion into concat buffers ----
  k_cvt_cols<<<cdiv(NL * 256, 256), 256, 0, stream>>>(x_l, cat16, NL, 1024, 1792, 0);
  k_cvt_cols<<<cdiv(NJ * 64, 256), 256, 0, stream>>>(x_j, catJ, NJ, 256, 448, 0);

  // ---- CSR build for both graphs ----
  k_count2<<<cdiv(EL + EJ, 256), 256, 0, stream>>>(ei_l + EL, EL, cntL, ei_j + EJ, EJ, cntJ);
  k_scan4<<<1, 1024, 0, stream>>>(cntL, NL, rsL, disL);
  k_scan4<<<1, 1024, 0, stream>>>(cntJ, NJ, rsJ, disJ);
  k_fill2<<<cdiv(EL + EJ, 256), 256, 0, stream>>>(ei_l, EL, rsL, fillL, cixL,
                                                  ei_j, EJ, rsJ, fillJ, cixJ);

  // ================= line branch =================
  // GCN layer 1: 1024 -> 512
  gemm(cat16, 1792, W1t, xw16, 512, nullptr, 0, 0, NL, 512, 1024);
  k_gather_f16<8><<<cdiv(NL, 4), 256, 0, stream>>>(xw16, 512, rsL, cixL, disL, lgb1,
                                                   cat16, 1792, 1024, NL);
  bn(cat16, 1792, 1024, NL, 512, sum1L, sq1L, lgg1, lgbe1);

  // GCN layer 2: 512 -> 256
  gemm(cat16 + 1024, 1792, W2t, xw16, 256, nullptr, 0, 0, NL, 256, 512);
  k_gather_f16<4><<<cdiv(NL, 4), 256, 0, stream>>>(xw16, 256, rsL, cixL, disL, lgb2,
                                                   cat16, 1792, 1536, NL);
  bn(cat16, 1792, 1536, NL, 256, sum2L, sq2L, lgg2, lgbe2);

  // fc over concat(1792) + fl stack + final logits (fp32 out, MFMA)
  gemm(cat16, 1792, fcWt, hA, 1024, lgfcb, 1, 0, NL, 1024, 1792);
  gemm(hA, 1024, flW1t, hB, 1024, flb1, 1, 0, NL, 1024, 1024);
  gemm(hB, 1024, flW2t, hA, 1024, flb2, 1, 0, NL, 1024, 1024);
  gemm(hA, 1024, flW3t, (float*)d_out, 10, flb3, 0, 1, NL, 10, 1024);

  // ================= junction branch =================
  gemm(catJ, 448, jW1t, xwJ, 128, nullptr, 0, 0, NJ, 128, 256);
  k_gather_f16<2><<<cdiv(NJ, 4), 256, 0, stream>>>(xwJ, 128, rsJ, cixJ, disJ, jgb1,
                                                   catJ, 448, 256, NJ);
  bn(catJ, 448, 256, NJ, 128, sum1J, sq1J, jgg1, jgbe1);

  gemm(catJ + 256, 448, jW2t, xwJ, 64, nullptr, 0, 0, NJ, 64, 128);
  k_gather_f16<1><<<cdiv(NJ, 4), 256, 0, stream>>>(xwJ, 64, rsJ, cixJ, disJ, jgb2,
                                                   catJ, 448, 384, NJ);
  bn(catJ, 448, 384, NJ, 64, sum2J, sq2J, jgg2, jgbe2);

  gemm(catJ, 448, jfcWt, hJA, 256, jgfcb, 1, 0, NJ, 256, 448);
  gemm(hJA, 256, fjW1t, hJB, 64, fjb1, 1, 0, NJ, 64, 256);
  gemm(hJB, 64, fjW2t, (float*)d_out + (size_t)NL * 10, 3, fjb2, 0, 1, NJ, 3, 64);
}

// Round 5
// 1496.399 us; speedup vs baseline: 1.1742x; 1.0065x over previous
//
#include <hip/hip_runtime.h>
#include <stdint.h>
#include <stddef.h>

typedef _Float16 f16;
typedef _Float16 f16x8 __attribute__((ext_vector_type(8)));
typedef _Float16 f16x4_t __attribute__((ext_vector_type(4)));
typedef float floatx4 __attribute__((ext_vector_type(4)));

template <int N> struct F16Vec { typedef f16 type __attribute__((ext_vector_type(N))); };

#define BN_EPS 1e-5f

// ---------------------------------------------------------------------------
// batched LDS-tiled weight transpose-convert: W [K,N] fp32 -> Wt [N,K] fp16
// ---------------------------------------------------------------------------
struct WtJob { const float* W; f16* Wt; int K; int N; int tN; int tilebase; };
struct WtBatch { WtJob j[12]; int njobs; int ntiles; };

__global__ void k_wt_tiled(WtBatch b) {
  __shared__ float T[32][33];
  int bt = blockIdx.x;
  int i = 0;
  #pragma unroll 1
  while (i + 1 < b.njobs && bt >= b.j[i + 1].tilebase) ++i;
  WtJob J = b.j[i];
  int t = bt - J.tilebase;
  int tr = t / J.tN, tc = t - tr * J.tN;      // K-tile, N-tile
  int ty = threadIdx.x >> 5, tx = threadIdx.x & 31;
  #pragma unroll
  for (int s = 0; s < 32; s += 8) {
    int k = tr * 32 + ty + s, n = tc * 32 + tx;
    if (k < J.K && n < J.N) T[ty + s][tx] = J.W[(size_t)k * J.N + n];
  }
  __syncthreads();
  #pragma unroll
  for (int s = 0; s < 32; s += 8) {
    int n = tc * 32 + ty + s, k = tr * 32 + tx;
    if (n < J.N && k < J.K) J.Wt[(size_t)n * J.K + k] = (f16)T[tx][ty + s];
  }
}

// fp32 [n,c] -> fp16 into dst[r*ldd + coff + j]  (c % 4 == 0)
__global__ void k_cvt_cols(const float* __restrict__ src, f16* __restrict__ dst,
                           int n, int c, int ldd, int coff) {
  int t = blockIdx.x * blockDim.x + threadIdx.x;
  int cq = c >> 2;
  if (t >= n * cq) return;
  int r = t / cq, j = (t - r * cq) << 2;
  float4 v = *(const float4*)(src + (size_t)r * c + j);
  f16x4_t o; o[0] = (f16)v.x; o[1] = (f16)v.y; o[2] = (f16)v.z; o[3] = (f16)v.w;
  *(f16x4_t*)(dst + (size_t)r * ldd + coff + j) = o;
}

// ---------------------------------------------------------------------------
// CSR build (both graphs fused where possible)
// ---------------------------------------------------------------------------
__global__ void k_count2(const int* __restrict__ dL, int EL, int* __restrict__ cntL,
                         const int* __restrict__ dJ, int EJ, int* __restrict__ cntJ) {
  int t = blockIdx.x * blockDim.x + threadIdx.x;
  if (t < EL) atomicAdd(&cntL[dL[t]], 1);
  else if (t < EL + EJ) atomicAdd(&cntJ[dJ[t - EL]], 1);
}

// 1024 threads, 4 elems/thread/strip; n % 4 == 0
__global__ void k_scan4(const int* __restrict__ cnt, int n, int* __restrict__ rowstart,
                        float* __restrict__ dis) {
  __shared__ int wsum[16];
  __shared__ int carry_s;
  int tid = threadIdx.x, lane = tid & 63, wv = tid >> 6;
  if (tid == 0) { carry_s = 0; rowstart[0] = 0; }
  __syncthreads();
  for (int base = 0; base < n; base += 4096) {
    int i4 = base + tid * 4;
    int4 c = {0, 0, 0, 0};
    if (i4 < n) c = *(const int4*)(cnt + i4);
    int s0 = c.x, s1 = s0 + c.y, s2 = s1 + c.z, s3 = s2 + c.w;
    int x = s3;
    #pragma unroll
    for (int off = 1; off < 64; off <<= 1) {
      int y = __shfl_up(x, off, 64);
      if (lane >= off) x += y;
    }
    if (lane == 63) wsum[wv] = x;
    __syncthreads();
    if (wv == 0) {
      int s = (lane < 16) ? wsum[lane] : 0;
      #pragma unroll
      for (int off = 1; off < 16; off <<= 1) {
        int y = __shfl_up(s, off, 64);
        if (lane >= off) s += y;
      }
      if (lane < 16) wsum[lane] = s;
    }
    __syncthreads();
    int waveoff = (wv == 0) ? 0 : wsum[wv - 1];
    int excl = (x - s3) + waveoff + carry_s;   // exclusive prefix for this thread
    if (i4 < n) {
      rowstart[i4 + 1] = excl + s0;
      rowstart[i4 + 2] = excl + s1;
      rowstart[i4 + 3] = excl + s2;
      rowstart[i4 + 4] = excl + s3;
      dis[i4 + 0] = rsqrtf(1.0f + (float)c.x);
      dis[i4 + 1] = rsqrtf(1.0f + (float)c.y);
      dis[i4 + 2] = rsqrtf(1.0f + (float)c.z);
      dis[i4 + 3] = rsqrtf(1.0f + (float)c.w);
    }
    __syncthreads();
    if (tid == 1023) carry_s = excl + s3;
    __syncthreads();
  }
}

__global__ void k_fill2(const int* __restrict__ eiL, int EL, const int* __restrict__ rsL,
                        int* __restrict__ fillL, int* __restrict__ cixL,
                        const int* __restrict__ eiJ, int EJ, const int* __restrict__ rsJ,
                        int* __restrict__ fillJ, int* __restrict__ cixJ) {
  int t = blockIdx.x * blockDim.x + threadIdx.x;
  if (t < EL) {
    int s = eiL[t], d = eiL[EL + t];
    int pos = atomicAdd(&fillL[d], 1);
    cixL[rsL[d] + pos] = s;
  } else if (t < EL + EJ) {
    int u = t - EL;
    int s = eiJ[u], d = eiJ[EJ + u];
    int pos = atomicAdd(&fillJ[d], 1);
    cixJ[rsJ[d] + pos] = s;
  }
}

// ---------------------------------------------------------------------------
// GCN aggregation: one WAVE per node, CPL channels/lane, writes f16 into the
// concat slice (bias folded). acc fp32.
// ---------------------------------------------------------------------------
template <int CPL>
__global__ void k_gather_f16(const f16* __restrict__ xw, int C,
                             const int* __restrict__ rowstart, const int* __restrict__ colidx,
                             const float* __restrict__ dis, const float* __restrict__ bias,
                             f16* __restrict__ dst, int ldd, int coff, int n) {
  typedef typename F16Vec<CPL>::type V;
  int w = threadIdx.x >> 6, l = threadIdx.x & 63;
  int j = blockIdx.x * 4 + w;
  if (j >= n) return;
  float dj = dis[j];
  int rs = rowstart[j], re = rowstart[j + 1];
  int c0 = l * CPL;
  float acc[CPL];
  {
    V p = *(const V*)(xw + (size_t)j * C + c0);
    float s = dj * dj;
    #pragma unroll
    for (int t = 0; t < CPL; ++t) acc[t] = (float)p[t] * s;
  }
  int e = rs;
  for (; e + 2 <= re; e += 2) {
    int s0 = colidx[e], s1 = colidx[e + 1];
    float f0 = dis[s0] * dj, f1 = dis[s1] * dj;
    V p0 = *(const V*)(xw + (size_t)s0 * C + c0);
    V p1 = *(const V*)(xw + (size_t)s1 * C + c0);
    #pragma unroll
    for (int t = 0; t < CPL; ++t) acc[t] += (float)p0[t] * f0 + (float)p1[t] * f1;
  }
  if (e < re) {
    int s0 = colidx[e];
    float f0 = dis[s0] * dj;
    V p0 = *(const V*)(xw + (size_t)s0 * C + c0);
    #pragma unroll
    for (int t = 0; t < CPL; ++t) acc[t] += (float)p0[t] * f0;
  }
  V o;
  #pragma unroll
  for (int t = 0; t < CPL; ++t) o[t] = (f16)(acc[t] + bias[c0 + t]);
  *(V*)(dst + (size_t)j * ldd + coff + c0) = o;
}

// ---------------------------------------------------------------------------
// BatchNorm over f16 slice: stats -> params -> apply(+relu) in place
// ---------------------------------------------------------------------------
__global__ void k_stats(const f16* __restrict__ v, int ldd, int coff, int n, int C,
                        float* __restrict__ sum, float* __restrict__ sumsq) {
  int c = blockIdx.x * blockDim.x + threadIdx.x;
  if (c >= C) return;
  int r0 = blockIdx.y * 128, r1 = min(r0 + 128, n);
  float s = 0.f, s2 = 0.f;
  for (int r = r0; r < r1; ++r) {
    float x = (float)v[(size_t)r * ldd + coff + c];
    s += x; s2 += x * x;
  }
  atomicAdd(&sum[c], s);
  atomicAdd(&sumsq[c], s2);
}

__global__ void k_bnparam(const float* __restrict__ sum, const float* __restrict__ sumsq,
                          const float* __restrict__ gamma, const float* __restrict__ beta,
                          int n, int C, float* __restrict__ scale, float* __restrict__ shift) {
  int c = blockIdx.x * blockDim.x + threadIdx.x;
  if (c >= C) return;
  float mean = sum[c] / (float)n;
  float var = sumsq[c] / (float)n - mean * mean;
  float sc = gamma[c] * rsqrtf(var + BN_EPS);
  scale[c] = sc;
  shift[c] = beta[c] - mean * sc;
}

__global__ void k_bnapply_ip(f16* __restrict__ v, int ldd, int coff, int n, int C,
                             const float* __restrict__ scale, const float* __restrict__ shift) {
  int t = blockIdx.x * blockDim.x + threadIdx.x;
  int cq = C >> 2;
  if (t >= n * cq) return;
  int r = t / cq, c = (t - r * cq) << 2;
  f16* p = v + (size_t)r * ldd + coff + c;
  f16x4_t x = *(f16x4_t*)p;
  float4 sc = *(const float4*)(scale + c);
  float4 sh = *(const float4*)(shift + c);
  f16x4_t o;
  o[0] = (f16)fmaxf((float)x[0] * sc.x + sh.x, 0.f);
  o[1] = (f16)fmaxf((float)x[1] * sc.y + sh.y, 0.f);
  o[2] = (f16)fmaxf((float)x[2] * sc.z + sh.z, 0.f);
  o[3] = (f16)fmaxf((float)x[3] * sc.w + sh.w, 0.f);
  *(f16x4_t*)p = o;
}

// ---------------------------------------------------------------------------
// fp16 MFMA GEMM (small/odd shapes): C[M,N] = A[M,K] @ Bt[N,K]^T  (+bias,+relu)
// 128x128 tile, 4 waves, BK=32, double-buffered global_load_lds. (unchanged)
// ---------------------------------------------------------------------------
__global__ __launch_bounds__(256)
void k_gemm(const f16* __restrict__ A, int lda,
            const f16* __restrict__ Bt,
            void* __restrict__ Cv, int ldc,
            const float* __restrict__ bias, int relu, int outf,
            int M, int N, int K, int mt, int nt, int per) {
  __shared__ f16 Ash[2][128 * 32];   // 2 x 8 KB
  __shared__ f16 Bsh[2][128 * 32];
  int b = blockIdx.x;
  int g = (b & 7) * per + (b >> 3);
  if (g >= mt * nt) return;
  int tm = (g / nt) * 128, tn = (g % nt) * 128;
  int tid = threadIdx.x, l = tid & 63, w = tid >> 6;

  const f16* ag[2]; const f16* bg[2];
  uint32_t lof[2];
  #pragma unroll
  for (int j = 0; j < 2; ++j) {
    int rl = w * 32 + j * 16 + (l >> 2);
    int ck = l & 3;
    int lc = ck ^ ((rl >> 1) & 3);
    int gr = tm + rl; if (gr > M - 1) gr = M - 1;
    int gn = tn + rl; if (gn > N - 1) gn = N - 1;
    ag[j] = A + (size_t)gr * lda + lc * 8;
    bg[j] = Bt + (size_t)gn * K + lc * 8;
    lof[j] = (uint32_t)(w * 32 + j * 16) * 64;
  }

  int wm = (w >> 1) * 64, wn = (w & 1) * 64;
  int q = l >> 4, l15 = l & 15;
  uint32_t aoffb[4], boffb[4];
  #pragma unroll
  for (int i = 0; i < 4; ++i) {
    int m = wm + i * 16 + l15;
    int n2 = wn + i * 16 + l15;
    aoffb[i] = (uint32_t)(m * 32 + (q ^ ((m >> 1) & 3)) * 8) * 2;
    boffb[i] = (uint32_t)(n2 * 32 + (q ^ ((n2 >> 1) & 3)) * 8) * 2;
  }

  floatx4 acc[4][4];
  #pragma unroll
  for (int i = 0; i < 4; ++i)
    #pragma unroll
    for (int j = 0; j < 4; ++j) acc[i][j] = (floatx4){0.f, 0.f, 0.f, 0.f};

  int nk = K >> 5;
  #pragma unroll
  for (int j = 0; j < 2; ++j) {
    __builtin_amdgcn_global_load_lds(
        (const __attribute__((address_space(1))) void*)ag[j],
        (__attribute__((address_space(3))) void*)((char*)Ash + lof[j]), 16, 0, 0);
    __builtin_amdgcn_global_load_lds(
        (const __attribute__((address_space(1))) void*)bg[j],
        (__attribute__((address_space(3))) void*)((char*)Bsh + lof[j]), 16, 0, 0);
    ag[j] += 32; bg[j] += 32;
  }

  for (int i = 0; i < nk; ++i) {
    __syncthreads();
    if (i + 1 < nk) {
      uint32_t d = ((i + 1) & 1) ? 8192u : 0u;
      #pragma unroll
      for (int j = 0; j < 2; ++j) {
        __builtin_amdgcn_global_load_lds(
            (const __attribute__((address_space(1))) void*)ag[j],
            (__attribute__((address_space(3))) void*)((char*)Ash + d + lof[j]), 16, 0, 0);
        __builtin_amdgcn_global_load_lds(
            (const __attribute__((address_space(1))) void*)bg[j],
            (__attribute__((address_space(3))) void*)((char*)Bsh + d + lof[j]), 16, 0, 0);
        ag[j] += 32; bg[j] += 32;
      }
    }
    uint32_t s = (i & 1) ? 8192u : 0u;
    f16x8 af[4], bf[4];
    #pragma unroll
    for (int ii = 0; ii < 4; ++ii) {
      af[ii] = *(const f16x8*)((const char*)Ash + s + aoffb[ii]);
      bf[ii] = *(const f16x8*)((const char*)Bsh + s + boffb[ii]);
    }
    #pragma unroll
    for (int mi = 0; mi < 4; ++mi)
      #pragma unroll
      for (int ni = 0; ni < 4; ++ni)
        acc[mi][ni] = __builtin_amdgcn_mfma_f32_16x16x32_f16(af[mi], bf[ni], acc[mi][ni], 0, 0, 0);
  }

  #pragma unroll
  for (int ni = 0; ni < 4; ++ni) {
    int col = tn + wn + ni * 16 + l15;
    if (col >= N) continue;
    float bv = bias ? bias[col] : 0.f;
    #pragma unroll
    for (int mi = 0; mi < 4; ++mi) {
      int rowb = tm + wm + mi * 16 + q * 4;
      #pragma unroll
      for (int r = 0; r < 4; ++r) {
        int row = rowb + r;
        if (row < M) {
          float v = acc[mi][ni][r] + bv;
          if (relu) v = fmaxf(v, 0.f);
          if (outf) ((float*)Cv)[(size_t)row * ldc + col] = v;
          else      ((f16*)Cv)[(size_t)row * ldc + col] = (f16)v;
        }
      }
    }
  }
}

// ---------------------------------------------------------------------------
// 256x256 8-wave GEMM, mi-pair 4-phase schedule, m201-faithful sync (v4):
//   C[M,N] = A[M,K] @ Bt[N,K]^T (+bias,+relu), f16 out. BK=64, 512 threads.
// Each phase: {reads; stage; s_barrier; lgkmcnt(0); setprio(1); 16 MFMA;
// setprio(0); s_barrier}. Reads issue BEFORE the pre-MFMA barrier so their
// port time hides in the barrier-convergence window and the post-barrier
// lgkm drain is nearly free (the r2/r3 orderings put reads after the
// phase-head barrier -> read time fully serialized with the MFMA window).
// Stage rotation (unchanged, audited under new ordering — every DMA
// overwrite lands >=2 barriers after its region's last reader's lgkm drain):
//   p0: SA0(t+1->ob); p1: SA1(t+1->ob); p2: SB0(t+2->cb); p3: SB1(t+2->cb)
// vmcnt(4) gate once per K-tile at p0 head (retires exactly A(t)+B(t),
// leaves B(t+1) 4 loads in flight); vmcnt(0) on last iter.
// MFMA operands SWAPPED: acc = mfma(bf, af, acc) => lane holds 4 consecutive
// n at fixed m => f16x4 epilogue stores. MFMA emission interleaved so
// adjacent MFMAs never share an accumulator.
// ---------------------------------------------------------------------------
#define G_BAR()   __builtin_amdgcn_s_barrier()
#define G_LGKM0() asm volatile("s_waitcnt lgkmcnt(0)" ::: "memory")

#define READ_BF_ALL()                                                         \
  _Pragma("unroll")                                                           \
  for (int ni = 0; ni < 4; ++ni) {                                            \
    bf[ni][0] = *(const f16x8*)(cbp + bbase + ni * 2048 + cof0);              \
    bf[ni][1] = *(const f16x8*)(cbp + bbase + ni * 2048 + cof1);              \
  }

#define READ_AFP(P)                                                           \
  afp[0][0] = *(const f16x8*)(cbp + abase + (2 * (P)) * 2048 + cof0);         \
  afp[0][1] = *(const f16x8*)(cbp + abase + (2 * (P)) * 2048 + cof1);         \
  afp[1][0] = *(const f16x8*)(cbp + abase + (2 * (P) + 1) * 2048 + cof0);     \
  afp[1][1] = *(const f16x8*)(cbp + abase + (2 * (P) + 1) * 2048 + cof1);

#define MFMA_PAIR(P)                                                          \
  __builtin_amdgcn_s_setprio(1);                                              \
  _Pragma("unroll")                                                           \
  for (int ni = 0; ni < 4; ++ni) {                                            \
    acc[2*(P)][ni]   = __builtin_amdgcn_mfma_f32_16x16x32_f16(bf[ni][0], afp[0][0], acc[2*(P)][ni], 0, 0, 0);   \
    acc[2*(P)+1][ni] = __builtin_amdgcn_mfma_f32_16x16x32_f16(bf[ni][0], afp[1][0], acc[2*(P)+1][ni], 0, 0, 0); \
    acc[2*(P)][ni]   = __builtin_amdgcn_mfma_f32_16x16x32_f16(bf[ni][1], afp[0][1], acc[2*(P)][ni], 0, 0, 0);   \
    acc[2*(P)+1][ni] = __builtin_amdgcn_mfma_f32_16x16x32_f16(bf[ni][1], afp[1][1], acc[2*(P)+1][ni], 0, 0, 0); \
  }                                                                           \
  __builtin_amdgcn_s_setprio(0);

__global__ __launch_bounds__(512, 2)
void k_gemm256(const f16* __restrict__ A, int lda,
               const f16* __restrict__ Bt,
               f16* __restrict__ C, int ldc,
               const float* __restrict__ bias, int relu,
               int M, int N, int K, int mt, int nt) {
  __shared__ char lds[131072];
  char* ldsc = (char*)lds;
  int nwg = mt * nt;
  int b = blockIdx.x;
  // bijective XCD swizzle (m204)
  int xcd = b & 7, lid = b >> 3;
  int q8 = nwg >> 3, r8 = nwg & 7;
  int wg = (xcd < r8 ? xcd * (q8 + 1) : r8 * (q8 + 1) + (xcd - r8) * q8) + lid;
  int tm = (wg / nt) * 256, tn = (wg % nt) * 256;
  int tid = threadIdx.x, l = tid & 63, w = tid >> 6;
  int wm = w >> 2, wn = w & 3;            // 2 x 4 wave grid; wave tile 128x64
  int q = l >> 4, l15 = l & 15;
  int nk = K >> 6;

  // ---- staging: each thread owns 2 fixed (row, chunk) slots per half-tile ----
  int r0 = tid >> 3, r1 = r0 + 64;        // r1&7 == r0&7
  int ck = (tid & 7) ^ (r0 & 7);          // pre-swizzled global source chunk
  int gmA0a = tm + r0;        if (gmA0a > M - 1) gmA0a = M - 1;
  int gmA0b = tm + r1;        if (gmA0b > M - 1) gmA0b = M - 1;
  int gmA1a = tm + 128 + r0;  if (gmA1a > M - 1) gmA1a = M - 1;
  int gmA1b = tm + 128 + r1;  if (gmA1b > M - 1) gmA1b = M - 1;
  int gnB0a = tn + r0;        if (gnB0a > N - 1) gnB0a = N - 1;
  int gnB0b = tn + r1;        if (gnB0b > N - 1) gnB0b = N - 1;
  int gnB1a = tn + 128 + r0;  if (gnB1a > N - 1) gnB1a = N - 1;
  int gnB1b = tn + 128 + r1;  if (gnB1b > N - 1) gnB1b = N - 1;
  const f16* pA0a = A + (size_t)gmA0a * lda + ck * 8;
  const f16* pA0b = A + (size_t)gmA0b * lda + ck * 8;
  const f16* pA1a = A + (size_t)gmA1a * lda + ck * 8;
  const f16* pA1b = A + (size_t)gmA1b * lda + ck * 8;
  const f16* pB0a = Bt + (size_t)gnB0a * K + ck * 8;
  const f16* pB0b = Bt + (size_t)gnB0b * K + ck * 8;
  const f16* pB1a = Bt + (size_t)gnB1a * K + ck * 8;
  const f16* pB1b = Bt + (size_t)gnB1b * K + ck * 8;
  uint32_t dst0 = (uint32_t)tid * 16;

  auto ST2 = [&](const f16*& pa, const f16*& pb, uint32_t dst) {
    __builtin_amdgcn_global_load_lds(
        (const __attribute__((address_space(1))) void*)pa,
        (__attribute__((address_space(3))) void*)(ldsc + dst), 16, 0, 0);
    __builtin_amdgcn_global_load_lds(
        (const __attribute__((address_space(1))) void*)pb,
        (__attribute__((address_space(3))) void*)(ldsc + dst + 8192), 16, 0, 0);
    pa += 64; pb += 64;                   // advance one K-tile
  };
  auto SA0 = [&](uint32_t bb) { ST2(pA0a, pA0b, bb + dst0); };
  auto SA1 = [&](uint32_t bb) { ST2(pA1a, pA1b, bb + 16384u + dst0); };
  auto SB0 = [&](uint32_t bb) { ST2(pB0a, pB0b, bb + 32768u + dst0); };
  auto SB1 = [&](uint32_t bb) { ST2(pB1a, pB1b, bb + 49152u + dst0); };

  // ---- fragment read offsets (byte): row*128 + (chunk ^ (row&7))*16 ----
  uint32_t abase = (uint32_t)((wm * 128 + l15) * 128);
  uint32_t bbase = (uint32_t)(32768 + (wn * 64 + l15) * 128);
  uint32_t cof0 = (uint32_t)(((0 + q) ^ (l15 & 7)) * 16);   // ksub 0
  uint32_t cof1 = (uint32_t)(((4 + q) ^ (l15 & 7)) * 16);   // ksub 1

  floatx4 acc[8][4];
  #pragma unroll
  for (int i = 0; i < 8; ++i)
    #pragma unroll
    for (int j = 0; j < 4; ++j) acc[i][j] = (floatx4){0.f, 0.f, 0.f, 0.f};

  // ---- prologue: KT0 (8 loads, oldest) then B(1) (4 loads) ----
  SA0(0u); SA1(0u); SB0(0u); SB1(0u);
  if (nk > 1) { SB0(65536u); SB1(65536u); }

  f16x8 bf[4][2], afp[2][2];
  for (int t = 0; t < nk; ++t) {
    uint32_t cb = (t & 1) ? 65536u : 0u;
    uint32_t ob = 65536u - cb;
    const char* cbp = ldsc + cb;
    // ---- p0: gate; reads bf_all + af0; stage SA0(t+1); BAR; lgkm0; MFMA0; BAR
    if (t + 1 < nk) { asm volatile("s_waitcnt vmcnt(4)" ::: "memory"); }
    else            { asm volatile("s_waitcnt vmcnt(0)" ::: "memory"); }
    G_BAR();
    READ_BF_ALL();
    READ_AFP(0);
    if (t + 1 < nk) SA0(ob);
    G_BAR(); G_LGKM0();
    MFMA_PAIR(0);
    G_BAR();
    // ---- p1: reads af1; stage SA1(t+1); BAR; lgkm0; MFMA1; BAR ----
    READ_AFP(1);
    if (t + 1 < nk) SA1(ob);
    G_BAR(); G_LGKM0();
    MFMA_PAIR(1);
    G_BAR();
    // ---- p2: reads af2; stage SB0(t+2); BAR; lgkm0; MFMA2; BAR ----
    READ_AFP(2);
    if (t + 2 < nk) SB0(cb);
    G_BAR(); G_LGKM0();
    MFMA_PAIR(2);
    G_BAR();
    // ---- p3: reads af3; stage SB1(t+2); BAR; lgkm0; MFMA3 (trailing BAR
    //      is next iter's p0 entry barrier after the vmcnt gate) ----
    READ_AFP(3);
    if (t + 2 < nk) SB1(cb);
    G_BAR(); G_LGKM0();
    MFMA_PAIR(3);
  }

  // ---- epilogue: lane holds C[m][n0..n0+3] (swapped-operand layout) ----
  #pragma unroll
  for (int mi = 0; mi < 8; ++mi) {
    int m = tm + wm * 128 + mi * 16 + l15;
    if (m >= M) continue;
    f16* crow = C + (size_t)m * ldc;
    #pragma unroll
    for (int ni = 0; ni < 4; ++ni) {
      int n0 = tn + wn * 64 + ni * 16 + q * 4;
      floatx4 v = acc[mi][ni];
      if (bias) {
        float4 bv = *(const float4*)(bias + n0);
        v[0] += bv.x; v[1] += bv.y; v[2] += bv.z; v[3] += bv.w;
      }
      if (relu) {
        v[0] = fmaxf(v[0], 0.f); v[1] = fmaxf(v[1], 0.f);
        v[2] = fmaxf(v[2], 0.f); v[3] = fmaxf(v[3], 0.f);
      }
      f16x4_t o;
      o[0] = (f16)v[0]; o[1] = (f16)v[1]; o[2] = (f16)v[2]; o[3] = (f16)v[3];
      *(f16x4_t*)(crow + n0) = o;
    }
  }
}

// ---------------------------------------------------------------------------
// host orchestration
// ---------------------------------------------------------------------------
extern "C" void kernel_launch(void* const* d_in, const int* in_sizes, int n_in,
                              void* d_out, int out_size, void* d_ws, size_t ws_size,
                              hipStream_t stream) {
  (void)in_sizes; (void)n_in; (void)out_size; (void)ws_size;
  const int NL = 50000, NJ = 25000, EL = 400000, EJ = 100000;

  const float* x_l  = (const float*)d_in[0];
  const float* x_j  = (const float*)d_in[1];
  const int*   ei_l = (const int*)d_in[2];
  const int*   ei_j = (const int*)d_in[3];
  const float* lgW1 = (const float*)d_in[4];  const float* lgb1 = (const float*)d_in[5];
  const float* lgg1 = (const float*)d_in[6];  const float* lgbe1= (const float*)d_in[7];
  const float* lgW2 = (const float*)d_in[8];  const float* lgb2 = (const float*)d_in[9];
  const float* lgg2 = (const float*)d_in[10]; const float* lgbe2= (const float*)d_in[11];
  const float* lgfcW= (const float*)d_in[12]; const float* lgfcb= (const float*)d_in[13];
  const float* flW1 = (const float*)d_in[14]; const float* flb1 = (const float*)d_in[15];
  const float* flW2 = (const float*)d_in[16]; const float* flb2 = (const float*)d_in[17];
  const float* flW3 = (const float*)d_in[18]; const float* flb3 = (const float*)d_in[19];
  const float* jgW1 = (const float*)d_in[20]; const float* jgb1 = (const float*)d_in[21];
  const float* jgg1 = (const float*)d_in[22]; const float* jgbe1= (const float*)d_in[23];
  const float* jgW2 = (const float*)d_in[24]; const float* jgb2 = (const float*)d_in[25];
  const float* jgg2 = (const float*)d_in[26]; const float* jgbe2= (const float*)d_in[27];
  const float* jgfcW= (const float*)d_in[28]; const float* jgfcb= (const float*)d_in[29];
  const float* fjW1 = (const float*)d_in[30]; const float* fjb1 = (const float*)d_in[31];
  const float* fjW2 = (const float*)d_in[32]; const float* fjb2 = (const float*)d_in[33];

  char* ws = (char*)d_ws;
  size_t off = 0;
  auto alloc = [&](size_t bytes) -> char* {
    char* p = ws + off;
    off += (bytes + 255) & ~(size_t)255;
    return p;
  };

  f16* cat16 = (f16*)alloc((size_t)NL * 1792 * 2);   // [x | h1 | h2]
  f16* hA    = (f16*)alloc((size_t)NL * 1024 * 2);
  f16* hB    = (f16*)alloc((size_t)NL * 1024 * 2);
  f16*  xw16  = (f16*)hB;      // alias: GCN phase only (hB first written at fl1)
  f16* catJ  = (f16*)alloc((size_t)NJ * 448 * 2);
  f16* hJA   = (f16*)alloc((size_t)NJ * 256 * 2);
  f16* hJB   = (f16*)alloc((size_t)NJ * 64 * 2);
  f16*  xwJ   = (f16*)hB;      // junction branch runs after line branch

  f16* W1t   = (f16*)alloc((size_t)1024 * 512 * 2);
  f16* W2t   = (f16*)alloc((size_t)512 * 256 * 2);
  f16* fcWt  = (f16*)alloc((size_t)1792 * 1024 * 2);
  f16* flW1t = (f16*)alloc((size_t)1024 * 1024 * 2);
  f16* flW2t = (f16*)alloc((size_t)1024 * 1024 * 2);
  f16* flW3t = (f16*)alloc((size_t)1024 * 16 * 2);
  f16* jW1t  = (f16*)alloc((size_t)256 * 128 * 2);
  f16* jW2t  = (f16*)alloc((size_t)128 * 64 * 2);
  f16* jfcWt = (f16*)alloc((size_t)448 * 256 * 2);
  f16* fjW1t = (f16*)alloc((size_t)256 * 64 * 2);
  f16* fjW2t = (f16*)alloc((size_t)64 * 4 * 2);

  // zero-region: [cntL | fillL | cntJ | fillJ | stats(1920 f32)]
  int* zero0 = (int*)alloc(((size_t)2 * NL + 2 * NJ + 1920) * 4);
  int* cntL  = zero0;
  int* fillL = cntL + NL;
  int* cntJ  = fillL + NL;
  int* fillJ = cntJ + NJ;
  float* stats = (float*)(fillJ + NJ);
  float* sum1L = stats;        float* sq1L = stats + 512;    // C=512
  float* sum2L = stats + 1024; float* sq2L = stats + 1280;   // C=256
  float* sum1J = stats + 1536; float* sq1J = stats + 1664;   // C=128
  float* sum2J = stats + 1792; float* sq2J = stats + 1856;   // C=64

  int* rsL   = (int*)alloc((size_t)(NL + 4) * 4);
  int* cixL  = (int*)alloc((size_t)EL * 4);
  float* disL= (float*)alloc((size_t)NL * 4);
  int* rsJ   = (int*)alloc((size_t)(NJ + 4) * 4);
  int* cixJ  = (int*)alloc((size_t)EJ * 4);
  float* disJ= (float*)alloc((size_t)NJ * 4);
  float* scalc = (float*)alloc(512 * 4);
  float* shftc = (float*)alloc(512 * 4);

  auto cdiv = [](int a, int b) { return (a + b - 1) / b; };

  auto gemm = [&](const f16* A, int lda, const f16* Bt, void* Cc, int ldc,
                  const float* bias, int relu, int outf, int M, int N, int K) {
    if (!outf && (N & 255) == 0 && N >= 256 && (K & 63) == 0 && K >= 128) {
      // 256x256 4-phase mi-pair path (fc, fl1, fl2, GCN1, GCN2, jfc)
      int mt = cdiv(M, 256), nt = N >> 8;
      k_gemm256<<<mt * nt, 512, 0, stream>>>(A, lda, Bt, (f16*)Cc, ldc, bias, relu,
                                             M, N, K, mt, nt);
    } else {
      int mt = cdiv(M, 128), nt = cdiv(N, 128);
      int per = cdiv(mt * nt, 8);
      k_gemm<<<8 * per, 256, 0, stream>>>(A, lda, Bt, Cc, ldc, bias, relu, outf,
                                          M, N, K, mt, nt, per);
    }
  };
  auto bn = [&](f16* v, int ldd, int coff, int n, int C,
                float* sum, float* sumsq, const float* gamma, const float* beta) {
    dim3 gs(cdiv(C, 256), cdiv(n, 128));
    k_stats<<<gs, 256, 0, stream>>>(v, ldd, coff, n, C, sum, sumsq);
    k_bnparam<<<cdiv(C, 256), 256, 0, stream>>>(sum, sumsq, gamma, beta, n, C, scalc, shftc);
    k_bnapply_ip<<<cdiv(n * (C >> 2), 256), 256, 0, stream>>>(v, ldd, coff, n, C, scalc, shftc);
  };

  // ---- one memset for all zero-init scratch ----
  hipMemsetAsync(zero0, 0, ((size_t)2 * NL + 2 * NJ + 1920) * 4, stream);

  // ---- all weight transpose-converts in ONE tiled launch ----
  {
    WtBatch B2; int base = 0, nj = 0;
    auto add = [&](const float* W, f16* Wt, int K, int N) {
      int tK = cdiv(K, 32), tN = cdiv(N, 32);
      B2.j[nj++] = WtJob{W, Wt, K, N, tN, base};
      base += tK * tN;
    };
    add(lgW1, W1t, 1024, 512);
    add(lgW2, W2t, 512, 256);
    add(lgfcW, fcWt, 1792, 1024);
    add(flW1, flW1t, 1024, 1024);
    add(flW2, flW2t, 1024, 1024);
    add(flW3, flW3t, 1024, 10);
    add(jgW1, jW1t, 256, 128);
    add(jgW2, jW2t, 128, 64);
    add(jgfcW, jfcWt, 448, 256);
    add(fjW1, fjW1t, 256, 64);
    add(fjW2, fjW2t, 64, 3);
    B2.njobs = nj; B2.ntiles = base;
    k_wt_tiled<<<base, 256, 0, stream>>>(B2);
  }

  // ---- feature conversion into concat buffers ----
  k_cvt_cols<<<cdiv(NL * 256, 256), 256, 0, stream>>>(x_l, cat16, NL, 1024, 1792, 0);
  k_cvt_cols<<<cdiv(NJ * 64, 256), 256, 0, stream>>>(x_j, catJ, NJ, 256, 448, 0);

  // ---- CSR build for both graphs ----
  k_count2<<<cdiv(EL + EJ, 256), 256, 0, stream>>>(ei_l + EL, EL, cntL, ei_j + EJ, EJ, cntJ);
  k_scan4<<<1, 1024, 0, stream>>>(cntL, NL, rsL, disL);
  k_scan4<<<1, 1024, 0, stream>>>(cntJ, NJ, rsJ, disJ);
  k_fill2<<<cdiv(EL + EJ, 256), 256, 0, stream>>>(ei_l, EL, rsL, fillL, cixL,
                                                  ei_j, EJ, rsJ, fillJ, cixJ);

  // ================= line branch =================
  // GCN layer 1: 1024 -> 512
  gemm(cat16, 1792, W1t, xw16, 512, nullptr, 0, 0, NL, 512, 1024);
  k_gather_f16<8><<<cdiv(NL, 4), 256, 0, stream>>>(xw16, 512, rsL, cixL, disL, lgb1,
                                                   cat16, 1792, 1024, NL);
  bn(cat16, 1792, 1024, NL, 512, sum1L, sq1L, lgg1, lgbe1);

  // GCN layer 2: 512 -> 256
  gemm(cat16 + 1024, 1792, W2t, xw16, 256, nullptr, 0, 0, NL, 256, 512);
  k_gather_f16<4><<<cdiv(NL, 4), 256, 0, stream>>>(xw16, 256, rsL, cixL, disL, lgb2,
                                                   cat16, 1792, 1536, NL);
  bn(cat16, 1792, 1536, NL, 256, sum2L, sq2L, lgg2, lgbe2);

  // fc over concat(1792) + fl stack + final logits (fp32 out, MFMA)
  gemm(cat16, 1792, fcWt, hA, 1024, lgfcb, 1, 0, NL, 1024, 1792);
  gemm(hA, 1024, flW1t, hB, 1024, flb1, 1, 0, NL, 1024, 1024);
  gemm(hB, 1024, flW2t, hA, 1024, flb2, 1, 0, NL, 1024, 1024);
  gemm(hA, 1024, flW3t, (float*)d_out, 10, flb3, 0, 1, NL, 10, 1024);

  // ================= junction branch =================
  gemm(catJ, 448, jW1t, xwJ, 128, nullptr, 0, 0, NJ, 128, 256);
  k_gather_f16<2><<<cdiv(NJ, 4), 256, 0, stream>>>(xwJ, 128, rsJ, cixJ, disJ, jgb1,
                                                   catJ, 448, 256, NJ);
  bn(catJ, 448, 256, NJ, 128, sum1J, sq1J, jgg1, jgbe1);

  gemm(catJ + 256, 448, jW2t, xwJ, 64, nullptr, 0, 0, NJ, 64, 128);
  k_gather_f16<1><<<cdiv(NJ, 4), 256, 0, stream>>>(xwJ, 64, rsJ, cixJ, disJ, jgb2,
                                                   catJ, 448, 384, NJ);
  bn(catJ, 448, 384, NJ, 64, sum2J, sq2J, jgg2, jgbe2);

  gemm(catJ, 448, jfcWt, hJA, 256, jgfcb, 1, 0, NJ, 256, 448);
  gemm(hJA, 256, fjW1t, hJB, 64, fjb1, 1, 0, NJ, 64, 256);
  gemm(hJB, 64, fjW2t, (float*)d_out + (size_t)NL * 10, 3, fjb2, 0, 1, NJ, 3, 64);
}

// Round 6
// 1449.126 us; speedup vs baseline: 1.2125x; 1.0326x over previous
//
#include <hip/hip_runtime.h>
#include <stdint.h>
#include <stddef.h>

typedef _Float16 f16;
typedef _Float16 f16x8 __attribute__((ext_vector_type(8)));
typedef _Float16 f16x4_t __attribute__((ext_vector_type(4)));
typedef float floatx4 __attribute__((ext_vector_type(4)));

template <int N> struct F16Vec { typedef f16 type __attribute__((ext_vector_type(N))); };

#define BN_EPS 1e-5f

// ---------------------------------------------------------------------------
// batched LDS-tiled weight transpose-convert: W [K,N] fp32 -> Wt [N,K] fp16
// ---------------------------------------------------------------------------
struct WtJob { const float* W; f16* Wt; int K; int N; int tN; int tilebase; };
struct WtBatch { WtJob j[12]; int njobs; int ntiles; };

__global__ void k_wt_tiled(WtBatch b) {
  __shared__ float T[32][33];
  int bt = blockIdx.x;
  int i = 0;
  #pragma unroll 1
  while (i + 1 < b.njobs && bt >= b.j[i + 1].tilebase) ++i;
  WtJob J = b.j[i];
  int t = bt - J.tilebase;
  int tr = t / J.tN, tc = t - tr * J.tN;      // K-tile, N-tile
  int ty = threadIdx.x >> 5, tx = threadIdx.x & 31;
  #pragma unroll
  for (int s = 0; s < 32; s += 8) {
    int k = tr * 32 + ty + s, n = tc * 32 + tx;
    if (k < J.K && n < J.N) T[ty + s][tx] = J.W[(size_t)k * J.N + n];
  }
  __syncthreads();
  #pragma unroll
  for (int s = 0; s < 32; s += 8) {
    int n = tc * 32 + ty + s, k = tr * 32 + tx;
    if (n < J.N && k < J.K) J.Wt[(size_t)n * J.K + k] = (f16)T[tx][ty + s];
  }
}

// fp32 [n,c] -> fp16 into dst[r*ldd + coff + j]  (c % 4 == 0)
__global__ void k_cvt_cols(const float* __restrict__ src, f16* __restrict__ dst,
                           int n, int c, int ldd, int coff) {
  int t = blockIdx.x * blockDim.x + threadIdx.x;
  int cq = c >> 2;
  if (t >= n * cq) return;
  int r = t / cq, j = (t - r * cq) << 2;
  float4 v = *(const float4*)(src + (size_t)r * c + j);
  f16x4_t o; o[0] = (f16)v.x; o[1] = (f16)v.y; o[2] = (f16)v.z; o[3] = (f16)v.w;
  *(f16x4_t*)(dst + (size_t)r * ldd + coff + j) = o;
}

// ---------------------------------------------------------------------------
// CSR build (both graphs fused where possible)
// ---------------------------------------------------------------------------
__global__ void k_count2(const int* __restrict__ dL, int EL, int* __restrict__ cntL,
                         const int* __restrict__ dJ, int EJ, int* __restrict__ cntJ) {
  int t = blockIdx.x * blockDim.x + threadIdx.x;
  if (t < EL) atomicAdd(&cntL[dL[t]], 1);
  else if (t < EL + EJ) atomicAdd(&cntJ[dJ[t - EL]], 1);
}

// 1024 threads, 4 elems/thread/strip; n % 4 == 0
__global__ void k_scan4(const int* __restrict__ cnt, int n, int* __restrict__ rowstart,
                        float* __restrict__ dis) {
  __shared__ int wsum[16];
  __shared__ int carry_s;
  int tid = threadIdx.x, lane = tid & 63, wv = tid >> 6;
  if (tid == 0) { carry_s = 0; rowstart[0] = 0; }
  __syncthreads();
  for (int base = 0; base < n; base += 4096) {
    int i4 = base + tid * 4;
    int4 c = {0, 0, 0, 0};
    if (i4 < n) c = *(const int4*)(cnt + i4);
    int s0 = c.x, s1 = s0 + c.y, s2 = s1 + c.z, s3 = s2 + c.w;
    int x = s3;
    #pragma unroll
    for (int off = 1; off < 64; off <<= 1) {
      int y = __shfl_up(x, off, 64);
      if (lane >= off) x += y;
    }
    if (lane == 63) wsum[wv] = x;
    __syncthreads();
    if (wv == 0) {
      int s = (lane < 16) ? wsum[lane] : 0;
      #pragma unroll
      for (int off = 1; off < 16; off <<= 1) {
        int y = __shfl_up(s, off, 64);
        if (lane >= off) s += y;
      }
      if (lane < 16) wsum[lane] = s;
    }
    __syncthreads();
    int waveoff = (wv == 0) ? 0 : wsum[wv - 1];
    int excl = (x - s3) + waveoff + carry_s;   // exclusive prefix for this thread
    if (i4 < n) {
      rowstart[i4 + 1] = excl + s0;
      rowstart[i4 + 2] = excl + s1;
      rowstart[i4 + 3] = excl + s2;
      rowstart[i4 + 4] = excl + s3;
      dis[i4 + 0] = rsqrtf(1.0f + (float)c.x);
      dis[i4 + 1] = rsqrtf(1.0f + (float)c.y);
      dis[i4 + 2] = rsqrtf(1.0f + (float)c.z);
      dis[i4 + 3] = rsqrtf(1.0f + (float)c.w);
    }
    __syncthreads();
    if (tid == 1023) carry_s = excl + s3;
    __syncthreads();
  }
}

__global__ void k_fill2(const int* __restrict__ eiL, int EL, const int* __restrict__ rsL,
                        int* __restrict__ fillL, int* __restrict__ cixL,
                        const int* __restrict__ eiJ, int EJ, const int* __restrict__ rsJ,
                        int* __restrict__ fillJ, int* __restrict__ cixJ) {
  int t = blockIdx.x * blockDim.x + threadIdx.x;
  if (t < EL) {
    int s = eiL[t], d = eiL[EL + t];
    int pos = atomicAdd(&fillL[d], 1);
    cixL[rsL[d] + pos] = s;
  } else if (t < EL + EJ) {
    int u = t - EL;
    int s = eiJ[u], d = eiJ[EJ + u];
    int pos = atomicAdd(&fillJ[d], 1);
    cixJ[rsJ[d] + pos] = s;
  }
}

// ---------------------------------------------------------------------------
// GCN aggregation: one WAVE per node, CPL channels/lane, writes f16 into the
// concat slice (bias folded). acc fp32.
// ---------------------------------------------------------------------------
template <int CPL>
__global__ void k_gather_f16(const f16* __restrict__ xw, int C,
                             const int* __restrict__ rowstart, const int* __restrict__ colidx,
                             const float* __restrict__ dis, const float* __restrict__ bias,
                             f16* __restrict__ dst, int ldd, int coff, int n) {
  typedef typename F16Vec<CPL>::type V;
  int w = threadIdx.x >> 6, l = threadIdx.x & 63;
  int j = blockIdx.x * 4 + w;
  if (j >= n) return;
  float dj = dis[j];
  int rs = rowstart[j], re = rowstart[j + 1];
  int c0 = l * CPL;
  float acc[CPL];
  {
    V p = *(const V*)(xw + (size_t)j * C + c0);
    float s = dj * dj;
    #pragma unroll
    for (int t = 0; t < CPL; ++t) acc[t] = (float)p[t] * s;
  }
  int e = rs;
  for (; e + 2 <= re; e += 2) {
    int s0 = colidx[e], s1 = colidx[e + 1];
    float f0 = dis[s0] * dj, f1 = dis[s1] * dj;
    V p0 = *(const V*)(xw + (size_t)s0 * C + c0);
    V p1 = *(const V*)(xw + (size_t)s1 * C + c0);
    #pragma unroll
    for (int t = 0; t < CPL; ++t) acc[t] += (float)p0[t] * f0 + (float)p1[t] * f1;
  }
  if (e < re) {
    int s0 = colidx[e];
    float f0 = dis[s0] * dj;
    V p0 = *(const V*)(xw + (size_t)s0 * C + c0);
    #pragma unroll
    for (int t = 0; t < CPL; ++t) acc[t] += (float)p0[t] * f0;
  }
  V o;
  #pragma unroll
  for (int t = 0; t < CPL; ++t) o[t] = (f16)(acc[t] + bias[c0 + t]);
  *(V*)(dst + (size_t)j * ldd + coff + c0) = o;
}

// ---------------------------------------------------------------------------
// BatchNorm over f16 slice: stats -> params -> apply(+relu) in place
// ---------------------------------------------------------------------------
__global__ void k_stats(const f16* __restrict__ v, int ldd, int coff, int n, int C,
                        float* __restrict__ sum, float* __restrict__ sumsq) {
  int c = blockIdx.x * blockDim.x + threadIdx.x;
  if (c >= C) return;
  int r0 = blockIdx.y * 128, r1 = min(r0 + 128, n);
  float s = 0.f, s2 = 0.f;
  for (int r = r0; r < r1; ++r) {
    float x = (float)v[(size_t)r * ldd + coff + c];
    s += x; s2 += x * x;
  }
  atomicAdd(&sum[c], s);
  atomicAdd(&sumsq[c], s2);
}

__global__ void k_bnparam(const float* __restrict__ sum, const float* __restrict__ sumsq,
                          const float* __restrict__ gamma, const float* __restrict__ beta,
                          int n, int C, float* __restrict__ scale, float* __restrict__ shift) {
  int c = blockIdx.x * blockDim.x + threadIdx.x;
  if (c >= C) return;
  float mean = sum[c] / (float)n;
  float var = sumsq[c] / (float)n - mean * mean;
  float sc = gamma[c] * rsqrtf(var + BN_EPS);
  scale[c] = sc;
  shift[c] = beta[c] - mean * sc;
}

__global__ void k_bnapply_ip(f16* __restrict__ v, int ldd, int coff, int n, int C,
                             const float* __restrict__ scale, const float* __restrict__ shift) {
  int t = blockIdx.x * blockDim.x + threadIdx.x;
  int cq = C >> 2;
  if (t >= n * cq) return;
  int r = t / cq, c = (t - r * cq) << 2;
  f16* p = v + (size_t)r * ldd + coff + c;
  f16x4_t x = *(f16x4_t*)p;
  float4 sc = *(const float4*)(scale + c);
  float4 sh = *(const float4*)(shift + c);
  f16x4_t o;
  o[0] = (f16)fmaxf((float)x[0] * sc.x + sh.x, 0.f);
  o[1] = (f16)fmaxf((float)x[1] * sc.y + sh.y, 0.f);
  o[2] = (f16)fmaxf((float)x[2] * sc.z + sh.z, 0.f);
  o[3] = (f16)fmaxf((float)x[3] * sc.w + sh.w, 0.f);
  *(f16x4_t*)p = o;
}

// ---------------------------------------------------------------------------
// fp16 MFMA GEMM (small/odd shapes): C[M,N] = A[M,K] @ Bt[N,K]^T  (+bias,+relu)
// 128x128 tile, 4 waves, BK=32, double-buffered global_load_lds. (unchanged)
// ---------------------------------------------------------------------------
__global__ __launch_bounds__(256)
void k_gemm(const f16* __restrict__ A, int lda,
            const f16* __restrict__ Bt,
            void* __restrict__ Cv, int ldc,
            const float* __restrict__ bias, int relu, int outf,
            int M, int N, int K, int mt, int nt, int per) {
  __shared__ f16 Ash[2][128 * 32];   // 2 x 8 KB
  __shared__ f16 Bsh[2][128 * 32];
  int b = blockIdx.x;
  int g = (b & 7) * per + (b >> 3);
  if (g >= mt * nt) return;
  int tm = (g / nt) * 128, tn = (g % nt) * 128;
  int tid = threadIdx.x, l = tid & 63, w = tid >> 6;

  const f16* ag[2]; const f16* bg[2];
  uint32_t lof[2];
  #pragma unroll
  for (int j = 0; j < 2; ++j) {
    int rl = w * 32 + j * 16 + (l >> 2);
    int ck = l & 3;
    int lc = ck ^ ((rl >> 1) & 3);
    int gr = tm + rl; if (gr > M - 1) gr = M - 1;
    int gn = tn + rl; if (gn > N - 1) gn = N - 1;
    ag[j] = A + (size_t)gr * lda + lc * 8;
    bg[j] = Bt + (size_t)gn * K + lc * 8;
    lof[j] = (uint32_t)(w * 32 + j * 16) * 64;
  }

  int wm = (w >> 1) * 64, wn = (w & 1) * 64;
  int q = l >> 4, l15 = l & 15;
  uint32_t aoffb[4], boffb[4];
  #pragma unroll
  for (int i = 0; i < 4; ++i) {
    int m = wm + i * 16 + l15;
    int n2 = wn + i * 16 + l15;
    aoffb[i] = (uint32_t)(m * 32 + (q ^ ((m >> 1) & 3)) * 8) * 2;
    boffb[i] = (uint32_t)(n2 * 32 + (q ^ ((n2 >> 1) & 3)) * 8) * 2;
  }

  floatx4 acc[4][4];
  #pragma unroll
  for (int i = 0; i < 4; ++i)
    #pragma unroll
    for (int j = 0; j < 4; ++j) acc[i][j] = (floatx4){0.f, 0.f, 0.f, 0.f};

  int nk = K >> 5;
  #pragma unroll
  for (int j = 0; j < 2; ++j) {
    __builtin_amdgcn_global_load_lds(
        (const __attribute__((address_space(1))) void*)ag[j],
        (__attribute__((address_space(3))) void*)((char*)Ash + lof[j]), 16, 0, 0);
    __builtin_amdgcn_global_load_lds(
        (const __attribute__((address_space(1))) void*)bg[j],
        (__attribute__((address_space(3))) void*)((char*)Bsh + lof[j]), 16, 0, 0);
    ag[j] += 32; bg[j] += 32;
  }

  for (int i = 0; i < nk; ++i) {
    __syncthreads();
    if (i + 1 < nk) {
      uint32_t d = ((i + 1) & 1) ? 8192u : 0u;
      #pragma unroll
      for (int j = 0; j < 2; ++j) {
        __builtin_amdgcn_global_load_lds(
            (const __attribute__((address_space(1))) void*)ag[j],
            (__attribute__((address_space(3))) void*)((char*)Ash + d + lof[j]), 16, 0, 0);
        __builtin_amdgcn_global_load_lds(
            (const __attribute__((address_space(1))) void*)bg[j],
            (__attribute__((address_space(3))) void*)((char*)Bsh + d + lof[j]), 16, 0, 0);
        ag[j] += 32; bg[j] += 32;
      }
    }
    uint32_t s = (i & 1) ? 8192u : 0u;
    f16x8 af[4], bf[4];
    #pragma unroll
    for (int ii = 0; ii < 4; ++ii) {
      af[ii] = *(const f16x8*)((const char*)Ash + s + aoffb[ii]);
      bf[ii] = *(const f16x8*)((const char*)Bsh + s + boffb[ii]);
    }
    #pragma unroll
    for (int mi = 0; mi < 4; ++mi)
      #pragma unroll
      for (int ni = 0; ni < 4; ++ni)
        acc[mi][ni] = __builtin_amdgcn_mfma_f32_16x16x32_f16(af[mi], bf[ni], acc[mi][ni], 0, 0, 0);
  }

  #pragma unroll
  for (int ni = 0; ni < 4; ++ni) {
    int col = tn + wn + ni * 16 + l15;
    if (col >= N) continue;
    float bv = bias ? bias[col] : 0.f;
    #pragma unroll
    for (int mi = 0; mi < 4; ++mi) {
      int rowb = tm + wm + mi * 16 + q * 4;
      #pragma unroll
      for (int r = 0; r < 4; ++r) {
        int row = rowb + r;
        if (row < M) {
          float v = acc[mi][ni][r] + bv;
          if (relu) v = fmaxf(v, 0.f);
          if (outf) ((float*)Cv)[(size_t)row * ldc + col] = v;
          else      ((f16*)Cv)[(size_t)row * ldc + col] = (f16)v;
        }
      }
    }
  }
}

// ---------------------------------------------------------------------------
// 256x256 8-wave GEMM v5: COMPILER-SCHEDULED inner tile, minimal sync.
//   C[M,N] = A[M,K] @ Bt[N,K]^T (+bias,+relu), f16 out. BK=64, 512 threads.
// r2-r4 post-mortem: three phase orderings all ~32% MfmaUtil. Common factor:
// manual lgkmcnt(0) + barrier around every MFMA cluster (m141 anti-pattern)
// made LDS port time strictly disjoint from MFMA. v5 keeps ONLY the
// structurally required sync per K-tile:
//   head: vmcnt(4|0) gate + BAR + sched_barrier(0)
//         [gate retires everything <= t, leaves SB(t+1) in flight;
//          sched fence stops cb-reads hoisting above AND MFMA sinking below]
//   mid:  lgkmcnt(0) + BAR after the bf-consuming MFMA pair 0
//         [only cross-wave hazard: SB(t+2) overwrites cb-B, whose readers
//          (bf, all in pair 0) are drained by the lgkm0 on every wave]
// All fragment reads (24 ds_read_b128) and 64 MFMAs are otherwise FREE for
// the compiler to interleave with its own counted lgkmcnt waits (m97: that
// scheduling is near-optimal). No setprio (it is a sched fence here).
// Region audit: SA(t+1)->ob-A (readers = af of t-1, drained pre-head-BAR);
// SB(t+2)->cb-B (readers = bf of t, drained at mid); af2/af3 read cb-A
// (disjoint from both DMA targets). vmcnt ledger: before gate of t the only
// future-tile loads issued are SB(t+1) (4) -> vmcnt(4), last tile vmcnt(0).
// MFMA operands SWAPPED: acc = mfma(bf, af, acc) => lane holds 4 consecutive
// n at fixed m => f16x4 epilogue stores.
// ---------------------------------------------------------------------------
#define G_BAR()   __builtin_amdgcn_s_barrier()
#define G_LGKM0() asm volatile("s_waitcnt lgkmcnt(0)" ::: "memory")

#define READ_BF_ALL()                                                         \
  _Pragma("unroll")                                                           \
  for (int ni = 0; ni < 4; ++ni) {                                            \
    bf[ni][0] = *(const f16x8*)(cbp + bbase + ni * 2048 + cof0);              \
    bf[ni][1] = *(const f16x8*)(cbp + bbase + ni * 2048 + cof1);              \
  }

#define READ_AFP(DST, P)                                                      \
  DST[0] = *(const f16x8*)(cbp + abase + (2 * (P)) * 2048 + cof0);            \
  DST[1] = *(const f16x8*)(cbp + abase + (2 * (P)) * 2048 + cof1);            \
  DST[2] = *(const f16x8*)(cbp + abase + (2 * (P) + 1) * 2048 + cof0);        \
  DST[3] = *(const f16x8*)(cbp + abase + (2 * (P) + 1) * 2048 + cof1);

#define MFMA_PAIR(SRC, P)                                                     \
  _Pragma("unroll")                                                           \
  for (int ni = 0; ni < 4; ++ni) {                                            \
    acc[2*(P)][ni]   = __builtin_amdgcn_mfma_f32_16x16x32_f16(bf[ni][0], SRC[0], acc[2*(P)][ni], 0, 0, 0);   \
    acc[2*(P)+1][ni] = __builtin_amdgcn_mfma_f32_16x16x32_f16(bf[ni][0], SRC[2], acc[2*(P)+1][ni], 0, 0, 0); \
    acc[2*(P)][ni]   = __builtin_amdgcn_mfma_f32_16x16x32_f16(bf[ni][1], SRC[1], acc[2*(P)][ni], 0, 0, 0);   \
    acc[2*(P)+1][ni] = __builtin_amdgcn_mfma_f32_16x16x32_f16(bf[ni][1], SRC[3], acc[2*(P)+1][ni], 0, 0, 0); \
  }

__global__ __launch_bounds__(512, 2)
void k_gemm256(const f16* __restrict__ A, int lda,
               const f16* __restrict__ Bt,
               f16* __restrict__ C, int ldc,
               const float* __restrict__ bias, int relu,
               int M, int N, int K, int mt, int nt) {
  __shared__ char lds[131072];
  char* ldsc = (char*)lds;
  int nwg = mt * nt;
  int b = blockIdx.x;
  // bijective XCD swizzle (m204)
  int xcd = b & 7, lid = b >> 3;
  int q8 = nwg >> 3, r8 = nwg & 7;
  int wg = (xcd < r8 ? xcd * (q8 + 1) : r8 * (q8 + 1) + (xcd - r8) * q8) + lid;
  int tm = (wg / nt) * 256, tn = (wg % nt) * 256;
  int tid = threadIdx.x, l = tid & 63, w = tid >> 6;
  int wm = w >> 2, wn = w & 3;            // 2 x 4 wave grid; wave tile 128x64
  int q = l >> 4, l15 = l & 15;
  int nk = K >> 6;

  // ---- staging: each thread owns 2 fixed (row, chunk) slots per half-tile ----
  int r0 = tid >> 3, r1 = r0 + 64;        // r1&7 == r0&7
  int ck = (tid & 7) ^ (r0 & 7);          // pre-swizzled global source chunk
  int gmA0a = tm + r0;        if (gmA0a > M - 1) gmA0a = M - 1;
  int gmA0b = tm + r1;        if (gmA0b > M - 1) gmA0b = M - 1;
  int gmA1a = tm + 128 + r0;  if (gmA1a > M - 1) gmA1a = M - 1;
  int gmA1b = tm + 128 + r1;  if (gmA1b > M - 1) gmA1b = M - 1;
  int gnB0a = tn + r0;        if (gnB0a > N - 1) gnB0a = N - 1;
  int gnB0b = tn + r1;        if (gnB0b > N - 1) gnB0b = N - 1;
  int gnB1a = tn + 128 + r0;  if (gnB1a > N - 1) gnB1a = N - 1;
  int gnB1b = tn + 128 + r1;  if (gnB1b > N - 1) gnB1b = N - 1;
  const f16* pA0a = A + (size_t)gmA0a * lda + ck * 8;
  const f16* pA0b = A + (size_t)gmA0b * lda + ck * 8;
  const f16* pA1a = A + (size_t)gmA1a * lda + ck * 8;
  const f16* pA1b = A + (size_t)gmA1b * lda + ck * 8;
  const f16* pB0a = Bt + (size_t)gnB0a * K + ck * 8;
  const f16* pB0b = Bt + (size_t)gnB0b * K + ck * 8;
  const f16* pB1a = Bt + (size_t)gnB1a * K + ck * 8;
  const f16* pB1b = Bt + (size_t)gnB1b * K + ck * 8;
  uint32_t dst0 = (uint32_t)tid * 16;

  auto ST2 = [&](const f16*& pa, const f16*& pb, uint32_t dst) {
    __builtin_amdgcn_global_load_lds(
        (const __attribute__((address_space(1))) void*)pa,
        (__attribute__((address_space(3))) void*)(ldsc + dst), 16, 0, 0);
    __builtin_amdgcn_global_load_lds(
        (const __attribute__((address_space(1))) void*)pb,
        (__attribute__((address_space(3))) void*)(ldsc + dst + 8192), 16, 0, 0);
    pa += 64; pb += 64;                   // advance one K-tile
  };
  auto SA0 = [&](uint32_t bb) { ST2(pA0a, pA0b, bb + dst0); };
  auto SA1 = [&](uint32_t bb) { ST2(pA1a, pA1b, bb + 16384u + dst0); };
  auto SB0 = [&](uint32_t bb) { ST2(pB0a, pB0b, bb + 32768u + dst0); };
  auto SB1 = [&](uint32_t bb) { ST2(pB1a, pB1b, bb + 49152u + dst0); };

  // ---- fragment read offsets (byte): row*128 + (chunk ^ (row&7))*16 ----
  uint32_t abase = (uint32_t)((wm * 128 + l15) * 128);
  uint32_t bbase = (uint32_t)(32768 + (wn * 64 + l15) * 128);
  uint32_t cof0 = (uint32_t)(((0 + q) ^ (l15 & 7)) * 16);   // ksub 0
  uint32_t cof1 = (uint32_t)(((4 + q) ^ (l15 & 7)) * 16);   // ksub 1

  floatx4 acc[8][4];
  #pragma unroll
  for (int i = 0; i < 8; ++i)
    #pragma unroll
    for (int j = 0; j < 4; ++j) acc[i][j] = (floatx4){0.f, 0.f, 0.f, 0.f};

  // ---- prologue: KT0 (8 loads, oldest) then B(1) (4 loads) ----
  SA0(0u); SA1(0u); SB0(0u); SB1(0u);
  if (nk > 1) { SB0(65536u); SB1(65536u); }

  f16x8 bf[4][2], af0[4], af1[4], af2[4], af3[4];
  for (int t = 0; t < nk; ++t) {
    uint32_t cb = (t & 1) ? 65536u : 0u;
    uint32_t ob = 65536u - cb;
    const char* cbp = ldsc + cb;
    // ---- head: gate + barrier + sched fence ----
    if (t + 1 < nk) { asm volatile("s_waitcnt vmcnt(4)" ::: "memory"); }
    else            { asm volatile("s_waitcnt vmcnt(0)" ::: "memory"); }
    G_BAR();
    __builtin_amdgcn_sched_barrier(0);
    // stage A(t+1) into other buffer (readers of ob-A drained before head)
    if (t + 1 < nk) { SA0(ob); SA1(ob); }
    // reads + MFMA pair 0 (compiler inserts counted lgkm waits)
    READ_BF_ALL();
    READ_AFP(af0, 0);
    READ_AFP(af1, 1);
    MFMA_PAIR(af0, 0);
    // ---- mid: all waves' cb-B reads drained -> safe to overwrite cb-B ----
    G_LGKM0();
    G_BAR();
    if (t + 2 < nk) { SB0(cb); SB1(cb); }
    // remaining pairs, reads/MFMA freely interleaved by the compiler
    READ_AFP(af2, 2);
    MFMA_PAIR(af1, 1);
    READ_AFP(af3, 3);
    MFMA_PAIR(af2, 2);
    MFMA_PAIR(af3, 3);
  }

  // ---- epilogue: lane holds C[m][n0..n0+3] (swapped-operand layout) ----
  #pragma unroll
  for (int mi = 0; mi < 8; ++mi) {
    int m = tm + wm * 128 + mi * 16 + l15;
    if (m >= M) continue;
    f16* crow = C + (size_t)m * ldc;
    #pragma unroll
    for (int ni = 0; ni < 4; ++ni) {
      int n0 = tn + wn * 64 + ni * 16 + q * 4;
      floatx4 v = acc[mi][ni];
      if (bias) {
        float4 bv = *(const float4*)(bias + n0);
        v[0] += bv.x; v[1] += bv.y; v[2] += bv.z; v[3] += bv.w;
      }
      if (relu) {
        v[0] = fmaxf(v[0], 0.f); v[1] = fmaxf(v[1], 0.f);
        v[2] = fmaxf(v[2], 0.f); v[3] = fmaxf(v[3], 0.f);
      }
      f16x4_t o;
      o[0] = (f16)v[0]; o[1] = (f16)v[1]; o[2] = (f16)v[2]; o[3] = (f16)v[3];
      *(f16x4_t*)(crow + n0) = o;
    }
  }
}

// ---------------------------------------------------------------------------
// host orchestration
// ---------------------------------------------------------------------------
extern "C" void kernel_launch(void* const* d_in, const int* in_sizes, int n_in,
                              void* d_out, int out_size, void* d_ws, size_t ws_size,
                              hipStream_t stream) {
  (void)in_sizes; (void)n_in; (void)out_size; (void)ws_size;
  const int NL = 50000, NJ = 25000, EL = 400000, EJ = 100000;

  const float* x_l  = (const float*)d_in[0];
  const float* x_j  = (const float*)d_in[1];
  const int*   ei_l = (const int*)d_in[2];
  const int*   ei_j = (const int*)d_in[3];
  const float* lgW1 = (const float*)d_in[4];  const float* lgb1 = (const float*)d_in[5];
  const float* lgg1 = (const float*)d_in[6];  const float* lgbe1= (const float*)d_in[7];
  const float* lgW2 = (const float*)d_in[8];  const float* lgb2 = (const float*)d_in[9];
  const float* lgg2 = (const float*)d_in[10]; const float* lgbe2= (const float*)d_in[11];
  const float* lgfcW= (const float*)d_in[12]; const float* lgfcb= (const float*)d_in[13];
  const float* flW1 = (const float*)d_in[14]; const float* flb1 = (const float*)d_in[15];
  const float* flW2 = (const float*)d_in[16]; const float* flb2 = (const float*)d_in[17];
  const float* flW3 = (const float*)d_in[18]; const float* flb3 = (const float*)d_in[19];
  const float* jgW1 = (const float*)d_in[20]; const float* jgb1 = (const float*)d_in[21];
  const float* jgg1 = (const float*)d_in[22]; const float* jgbe1= (const float*)d_in[23];
  const float* jgW2 = (const float*)d_in[24]; const float* jgb2 = (const float*)d_in[25];
  const float* jgg2 = (const float*)d_in[26]; const float* jgbe2= (const float*)d_in[27];
  const float* jgfcW= (const float*)d_in[28]; const float* jgfcb= (const float*)d_in[29];
  const float* fjW1 = (const float*)d_in[30]; const float* fjb1 = (const float*)d_in[31];
  const float* fjW2 = (const float*)d_in[32]; const float* fjb2 = (const float*)d_in[33];

  char* ws = (char*)d_ws;
  size_t off = 0;
  auto alloc = [&](size_t bytes) -> char* {
    char* p = ws + off;
    off += (bytes + 255) & ~(size_t)255;
    return p;
  };

  f16* cat16 = (f16*)alloc((size_t)NL * 1792 * 2);   // [x | h1 | h2]
  f16* hA    = (f16*)alloc((size_t)NL * 1024 * 2);
  f16* hB    = (f16*)alloc((size_t)NL * 1024 * 2);
  f16*  xw16  = (f16*)hB;      // alias: GCN phase only (hB first written at fl1)
  f16* catJ  = (f16*)alloc((size_t)NJ * 448 * 2);
  f16* hJA   = (f16*)alloc((size_t)NJ * 256 * 2);
  f16* hJB   = (f16*)alloc((size_t)NJ * 64 * 2);
  f16*  xwJ   = (f16*)hB;      // junction branch runs after line branch

  f16* W1t   = (f16*)alloc((size_t)1024 * 512 * 2);
  f16* W2t   = (f16*)alloc((size_t)512 * 256 * 2);
  f16* fcWt  = (f16*)alloc((size_t)1792 * 1024 * 2);
  f16* flW1t = (f16*)alloc((size_t)1024 * 1024 * 2);
  f16* flW2t = (f16*)alloc((size_t)1024 * 1024 * 2);
  f16* flW3t = (f16*)alloc((size_t)1024 * 16 * 2);
  f16* jW1t  = (f16*)alloc((size_t)256 * 128 * 2);
  f16* jW2t  = (f16*)alloc((size_t)128 * 64 * 2);
  f16* jfcWt = (f16*)alloc((size_t)448 * 256 * 2);
  f16* fjW1t = (f16*)alloc((size_t)256 * 64 * 2);
  f16* fjW2t = (f16*)alloc((size_t)64 * 4 * 2);

  // zero-region: [cntL | fillL | cntJ | fillJ | stats(1920 f32)]
  int* zero0 = (int*)alloc(((size_t)2 * NL + 2 * NJ + 1920) * 4);
  int* cntL  = zero0;
  int* fillL = cntL + NL;
  int* cntJ  = fillL + NL;
  int* fillJ = cntJ + NJ;
  float* stats = (float*)(fillJ + NJ);
  float* sum1L = stats;        float* sq1L = stats + 512;    // C=512
  float* sum2L = stats + 1024; float* sq2L = stats + 1280;   // C=256
  float* sum1J = stats + 1536; float* sq1J = stats + 1664;   // C=128
  float* sum2J = stats + 1792; float* sq2J = stats + 1856;   // C=64

  int* rsL   = (int*)alloc((size_t)(NL + 4) * 4);
  int* cixL  = (int*)alloc((size_t)EL * 4);
  float* disL= (float*)alloc((size_t)NL * 4);
  int* rsJ   = (int*)alloc((size_t)(NJ + 4) * 4);
  int* cixJ  = (int*)alloc((size_t)EJ * 4);
  float* disJ= (float*)alloc((size_t)NJ * 4);
  float* scalc = (float*)alloc(512 * 4);
  float* shftc = (float*)alloc(512 * 4);

  auto cdiv = [](int a, int b) { return (a + b - 1) / b; };

  auto gemm = [&](const f16* A, int lda, const f16* Bt, void* Cc, int ldc,
                  const float* bias, int relu, int outf, int M, int N, int K) {
    if (!outf && (N & 255) == 0 && N >= 256 && (K & 63) == 0 && K >= 128) {
      // 256x256 compiler-scheduled path (fc, fl1, fl2, GCN1, GCN2, jfc)
      int mt = cdiv(M, 256), nt = N >> 8;
      k_gemm256<<<mt * nt, 512, 0, stream>>>(A, lda, Bt, (f16*)Cc, ldc, bias, relu,
                                             M, N, K, mt, nt);
    } else {
      int mt = cdiv(M, 128), nt = cdiv(N, 128);
      int per = cdiv(mt * nt, 8);
      k_gemm<<<8 * per, 256, 0, stream>>>(A, lda, Bt, Cc, ldc, bias, relu, outf,
                                          M, N, K, mt, nt, per);
    }
  };
  auto bn = [&](f16* v, int ldd, int coff, int n, int C,
                float* sum, float* sumsq, const float* gamma, const float* beta) {
    dim3 gs(cdiv(C, 256), cdiv(n, 128));
    k_stats<<<gs, 256, 0, stream>>>(v, ldd, coff, n, C, sum, sumsq);
    k_bnparam<<<cdiv(C, 256), 256, 0, stream>>>(sum, sumsq, gamma, beta, n, C, scalc, shftc);
    k_bnapply_ip<<<cdiv(n * (C >> 2), 256), 256, 0, stream>>>(v, ldd, coff, n, C, scalc, shftc);
  };

  // ---- one memset for all zero-init scratch ----
  hipMemsetAsync(zero0, 0, ((size_t)2 * NL + 2 * NJ + 1920) * 4, stream);

  // ---- all weight transpose-converts in ONE tiled launch ----
  {
    WtBatch B2; int base = 0, nj = 0;
    auto add = [&](const float* W, f16* Wt, int K, int N) {
      int tK = cdiv(K, 32), tN = cdiv(N, 32);
      B2.j[nj++] = WtJob{W, Wt, K, N, tN, base};
      base += tK * tN;
    };
    add(lgW1, W1t, 1024, 512);
    add(lgW2, W2t, 512, 256);
    add(lgfcW, fcWt, 1792, 1024);
    add(flW1, flW1t, 1024, 1024);
    add(flW2, flW2t, 1024, 1024);
    add(flW3, flW3t, 1024, 10);
    add(jgW1, jW1t, 256, 128);
    add(jgW2, jW2t, 128, 64);
    add(jgfcW, jfcWt, 448, 256);
    add(fjW1, fjW1t, 256, 64);
    add(fjW2, fjW2t, 64, 3);
    B2.njobs = nj; B2.ntiles = base;
    k_wt_tiled<<<base, 256, 0, stream>>>(B2);
  }

  // ---- feature conversion into concat buffers ----
  k_cvt_cols<<<cdiv(NL * 256, 256), 256, 0, stream>>>(x_l, cat16, NL, 1024, 1792, 0);
  k_cvt_cols<<<cdiv(NJ * 64, 256), 256, 0, stream>>>(x_j, catJ, NJ, 256, 448, 0);

  // ---- CSR build for both graphs ----
  k_count2<<<cdiv(EL + EJ, 256), 256, 0, stream>>>(ei_l + EL, EL, cntL, ei_j + EJ, EJ, cntJ);
  k_scan4<<<1, 1024, 0, stream>>>(cntL, NL, rsL, disL);
  k_scan4<<<1, 1024, 0, stream>>>(cntJ, NJ, rsJ, disJ);
  k_fill2<<<cdiv(EL + EJ, 256), 256, 0, stream>>>(ei_l, EL, rsL, fillL, cixL,
                                                  ei_j, EJ, rsJ, fillJ, cixJ);

  // ================= line branch =================
  // GCN layer 1: 1024 -> 512
  gemm(cat16, 1792, W1t, xw16, 512, nullptr, 0, 0, NL, 512, 1024);
  k_gather_f16<8><<<cdiv(NL, 4), 256, 0, stream>>>(xw16, 512, rsL, cixL, disL, lgb1,
                                                   cat16, 1792, 1024, NL);
  bn(cat16, 1792, 1024, NL, 512, sum1L, sq1L, lgg1, lgbe1);

  // GCN layer 2: 512 -> 256
  gemm(cat16 + 1024, 1792, W2t, xw16, 256, nullptr, 0, 0, NL, 256, 512);
  k_gather_f16<4><<<cdiv(NL, 4), 256, 0, stream>>>(xw16, 256, rsL, cixL, disL, lgb2,
                                                   cat16, 1792, 1536, NL);
  bn(cat16, 1792, 1536, NL, 256, sum2L, sq2L, lgg2, lgbe2);

  // fc over concat(1792) + fl stack + final logits (fp32 out, MFMA)
  gemm(cat16, 1792, fcWt, hA, 1024, lgfcb, 1, 0, NL, 1024, 1792);
  gemm(hA, 1024, flW1t, hB, 1024, flb1, 1, 0, NL, 1024, 1024);
  gemm(hB, 1024, flW2t, hA, 1024, flb2, 1, 0, NL, 1024, 1024);
  gemm(hA, 1024, flW3t, (float*)d_out, 10, flb3, 0, 1, NL, 10, 1024);

  // ================= junction branch =================
  gemm(catJ, 448, jW1t, xwJ, 128, nullptr, 0, 0, NJ, 128, 256);
  k_gather_f16<2><<<cdiv(NJ, 4), 256, 0, stream>>>(xwJ, 128, rsJ, cixJ, disJ, jgb1,
                                                   catJ, 448, 256, NJ);
  bn(catJ, 448, 256, NJ, 128, sum1J, sq1J, jgg1, jgbe1);

  gemm(catJ + 256, 448, jW2t, xwJ, 64, nullptr, 0, 0, NJ, 64, 128);
  k_gather_f16<1><<<cdiv(NJ, 4), 256, 0, stream>>>(xwJ, 64, rsJ, cixJ, disJ, jgb2,
                                                   catJ, 448, 384, NJ);
  bn(catJ, 448, 384, NJ, 64, sum2J, sq2J, jgg2, jgbe2);

  gemm(catJ, 448, jfcWt, hJA, 256, jgfcb, 1, 0, NJ, 256, 448);
  gemm(hJA, 256, fjW1t, hJB, 64, fjb1, 1, 0, NJ, 64, 256);
  gemm(hJB, 64, fjW2t, (float*)d_out + (size_t)NL * 10, 3, fjb2, 0, 1, NJ, 3, 64);
}